// Round 11
// baseline (112.303 us; speedup 1.0000x reference)
//
#include <hip/hip_runtime.h>
#include <math.h>

#define N_T 32768
#define L 65536
#define BATCH 64
#define NPAIR 32
#define NEV 8
#define NROOM 16
#define ROWP 258
#define DSTRIDE 132
#define TP2 9
#define TWO_PI 6.2831853071795864769f
#define INV_L (1.0f / 65536.0f)

__device__ __forceinline__ float2 cmul(float2 a, float2 b) {
    return make_float2(a.x * b.x - a.y * b.y, a.x * b.y + a.y * b.x);
}
// base-4 digit reversal of an 8-bit index (involution)
__device__ __forceinline__ int dr4(int p) {
    return ((p & 3) << 6) | ((p & 12) << 2) | ((p & 48) >> 2) | ((p & 192) >> 6);
}

// register radix-4 DIF butterfly (fwd)
__device__ __forceinline__ void bf4f(float2& a, float2& b, float2& c, float2& d,
                                     const float2* tw, int f, int q) {
    float2 t0 = make_float2(a.x + c.x, a.y + c.y);
    float2 t1 = make_float2(a.x - c.x, a.y - c.y);
    float2 t2 = make_float2(b.x + d.x, b.y + d.y);
    float2 u  = make_float2(b.x - d.x, b.y - d.y);
    float2 t3 = make_float2(u.y, -u.x);            // -i*u
    a = make_float2(t0.x + t2.x, t0.y + t2.y);
    b = cmul(make_float2(t1.x + t3.x, t1.y + t3.y), tw[f * q]);
    c = cmul(make_float2(t0.x - t2.x, t0.y - t2.y), tw[2 * f * q]);
    d = cmul(make_float2(t1.x - t3.x, t1.y - t3.y), tw[3 * f * q]);
}
// register radix-4 DIT butterfly (inv): exact inverse of bf4f
__device__ __forceinline__ void bf4i(float2& a, float2& b, float2& c, float2& d,
                                     const float2* tw, int f, int q) {
    float2 w1 = tw[f * q], w2 = tw[2 * f * q], w3 = tw[3 * f * q];
    float2 y0 = a;
    float2 y1 = cmul(b, make_float2(w1.x, -w1.y));
    float2 y2 = cmul(c, make_float2(w2.x, -w2.y));
    float2 y3 = cmul(d, make_float2(w3.x, -w3.y));
    float2 t0 = make_float2(y0.x + y2.x, y0.y + y2.y);
    float2 t2 = make_float2(y0.x - y2.x, y0.y - y2.y);
    float2 t1 = make_float2(y1.x + y3.x, y1.y + y3.y);
    float2 u  = make_float2(y1.x - y3.x, y1.y - y3.y);
    a = make_float2(t0.x + t1.x, t0.y + t1.y);
    b = make_float2(t2.x - u.y, t2.y + u.x);
    c = make_float2(t0.x - t1.x, t0.y - t1.y);
    d = make_float2(t2.x + u.y, t2.y - u.x);
}
__device__ __forceinline__ void bfly4_fwd(float2* A, int a0, int st, const float2* tw, int f, int q) {
    bf4f(A[a0], A[a0 + st], A[a0 + 2 * st], A[a0 + 3 * st], tw, f, q);
}
__device__ __forceinline__ void bfly4_inv(float2* A, int a0, int st, const float2* tw, int f, int q) {
    bf4i(A[a0], A[a0 + st], A[a0 + 2 * st], A[a0 + 3 * st], tw, f, q);
}

// ---- gating ----
__global__ void k_prep(const float* __restrict__ g, const float* __restrict__ w_room,
                       const float* __restrict__ b_room, const float* __restrict__ w_mix,
                       const float* __restrict__ b_mix,
                       float* __restrict__ wroom, float* __restrict__ mixv) {
    int b = threadIdx.x;
    if (b >= BATCH) return;
    float logits[NROOM];
    for (int r = 0; r < NROOM; r++) logits[r] = b_room[r];
    float acc_mix = b_mix[0];
    for (int d = 0; d < 128; d++) {
        float gv = g[b * 128 + d];
        for (int r = 0; r < NROOM; r++) logits[r] += gv * w_room[d * NROOM + r];
        acc_mix += gv * w_mix[d];
    }
    float m = logits[0];
    for (int r = 1; r < NROOM; r++) m = fmaxf(m, logits[r]);
    float s = 0.f;
    for (int r = 0; r < NROOM; r++) { logits[r] = expf(logits[r] - m); s += logits[r]; }
    float inv = 1.f / s;
    for (int r = 0; r < NROOM; r++) wroom[b * NROOM + r] = logits[r] * inv;
    mixv[b] = 1.f / (1.f + expf(-acc_mix));
}

// ---- fused dry+K build + fwd col FFT; 128 threads, 8 columns, 2-wave lockstep ----
__global__ __launch_bounds__(128) void k_fwd(const float* __restrict__ events,
                                             const int* __restrict__ indices,
                                             const float* __restrict__ rooms,
                                             const float* __restrict__ wroom,
                                             float* __restrict__ dryf, float2* __restrict__ C) {
    __shared__ float dtile[8 * DSTRIDE];   // [c][n2]
    __shared__ float ktile[8 * DSTRIDE];
    __shared__ float2 T[128 * TP2];
    __shared__ float2 tw[256];
    __shared__ float2 fine[256];
    int t = threadIdx.x;
    int a = blockIdx.x >> 5;
    int cg = blockIdx.x & 31;
    int c0 = cg * 8;
    float2* base = C + (size_t)a * L;
    for (int i = t; i < 256; i += 128) {
        float sv, cv;
        __sincosf(-TWO_PI * (float)i * (1.0f / 256.0f), &sv, &cv);
        tw[i] = make_float2(cv, sv);
        __sincosf(-TWO_PI * (float)i * INV_L, &sv, &cv);
        fine[i] = make_float2(cv, sv);
    }
    // staging: thread t owns row n2 = t (32B contiguous per lane)
    {
        int n2 = t;
        const float* eb = events + (size_t)a * NEV * N_T;
        const int* ib = indices + a * NEV;
        const float* wb = wroom + a * NROOM;
        float4 dA = make_float4(0.f, 0.f, 0.f, 0.f), dB = dA;
#pragma unroll
        for (int e = 0; e < NEV; e++) {
            int s = ib[e];
            if (n2 >= s) {
                const float* er = eb + e * N_T + ((n2 - s) << 8) + c0;
                float4 vA = *(const float4*)er;
                float4 vB = *(const float4*)(er + 4);
                dA.x += vA.x; dA.y += vA.y; dA.z += vA.z; dA.w += vA.w;
                dB.x += vB.x; dB.y += vB.y; dB.z += vB.z; dB.w += vB.w;
            }
        }
        float4 kA = make_float4(0.f, 0.f, 0.f, 0.f), kB = kA;
#pragma unroll
        for (int r = 0; r < NROOM; r++) {
            float w = wb[r];
            const float* rr = rooms + (size_t)r * N_T + (n2 << 8) + c0;
            float4 vA = *(const float4*)rr;
            float4 vB = *(const float4*)(rr + 4);
            kA.x += w * vA.x; kA.y += w * vA.y; kA.z += w * vA.z; kA.w += w * vA.w;
            kB.x += w * vB.x; kB.y += w * vB.y; kB.z += w * vB.z; kB.w += w * vB.w;
        }
        float* db = dryf + (size_t)a * N_T + (n2 << 8) + c0;
        *(float4*)db = dA;
        *(float4*)(db + 4) = dB;
        dtile[0 * DSTRIDE + n2] = dA.x; dtile[1 * DSTRIDE + n2] = dA.y;
        dtile[2 * DSTRIDE + n2] = dA.z; dtile[3 * DSTRIDE + n2] = dA.w;
        dtile[4 * DSTRIDE + n2] = dB.x; dtile[5 * DSTRIDE + n2] = dB.y;
        dtile[6 * DSTRIDE + n2] = dB.z; dtile[7 * DSTRIDE + n2] = dB.w;
        ktile[0 * DSTRIDE + n2] = kA.x; ktile[1 * DSTRIDE + n2] = kA.y;
        ktile[2 * DSTRIDE + n2] = kA.z; ktile[3 * DSTRIDE + n2] = kA.w;
        ktile[4 * DSTRIDE + n2] = kB.x; ktile[5 * DSTRIDE + n2] = kB.y;
        ktile[6 * DSTRIDE + n2] = kB.z; ktile[7 * DSTRIDE + n2] = kB.w;
    }
    __syncthreads();
    int j = t >> 3, c = t & 7;
    int n1 = c0 + c;
    float2 r[16];
#pragma unroll
    for (int m = 0; m < 8; m++) {
        int n2 = j + 16 * m;               // < 128
        r[m] = make_float2(dtile[c * DSTRIDE + n2], ktile[c * DSTRIDE + n2]);
    }
#pragma unroll
    for (int m = 8; m < 16; m++) r[m] = make_float2(0.f, 0.f);
#pragma unroll
    for (int m0 = 0; m0 < 4; m0++) bf4f(r[m0], r[m0 + 4], r[m0 + 8], r[m0 + 12], tw, 1, j + 16 * m0);
#pragma unroll
    for (int h = 0; h < 4; h++) bf4f(r[4 * h], r[4 * h + 1], r[4 * h + 2], r[4 * h + 3], tw, 4, j);
    // two-round transpose; round A = wave 0 reads, round B = wave 1 reads
    float2 r2[16];
#pragma unroll
    for (int m = 0; m < 8; m++) T[(j + 16 * m) * TP2 + c] = r[m];
    __syncthreads();
    if (j < 8) {
#pragma unroll
        for (int jj = 0; jj < 16; jj++) r2[jj] = T[(jj + 16 * j) * TP2 + c];
    }
    __syncthreads();
#pragma unroll
    for (int m = 8; m < 16; m++) T[(j + 16 * m - 128) * TP2 + c] = r[m];
    __syncthreads();
    if (j >= 8) {
#pragma unroll
        for (int jj = 0; jj < 16; jj++) r2[jj] = T[(jj + 16 * (j - 8)) * TP2 + c];
    }
#pragma unroll
    for (int q = 0; q < 4; q++) bf4f(r2[q], r2[q + 4], r2[q + 8], r2[q + 12], tw, 16, q);
#pragma unroll
    for (int h = 0; h < 4; h++) bf4f(r2[4 * h], r2[4 * h + 1], r2[4 * h + 2], r2[4 * h + 3], tw, 64, 0);
#pragma unroll
    for (int jj = 0; jj < 16; jj++) {
        int p = jj + 16 * j;
        int k2 = dr4(p);
        int ph = (n1 * k2) & (L - 1);
        float2 w = cmul(tw[ph >> 8], fine[ph & 255]);
        base[n1 + (p << 8)] = cmul(r2[jj], w);     // 8 lanes x float2 = 64B chunks
    }
}

// ---- pointwise unit (LDS form, rowpw) ----
__device__ __forceinline__ void pw_unit(float2* A, int sJ, int kJ, int sN, int kN) {
    float2 Z0j = A[sJ * ROWP + kJ],       Z0n = A[sN * ROWP + kN];
    float2 Z1j = A[(4 + sJ) * ROWP + kJ], Z1n = A[(4 + sN) * ROWP + kN];
    float2 D0 = make_float2(0.5f * (Z0j.x + Z0n.x), 0.5f * (Z0j.y - Z0n.y));
    float2 K0 = make_float2(0.5f * (Z0j.y + Z0n.y), 0.5f * (Z0n.x - Z0j.x));
    float2 D1 = make_float2(0.5f * (Z1j.x + Z1n.x), 0.5f * (Z1j.y - Z1n.y));
    float2 K1 = make_float2(0.5f * (Z1j.y + Z1n.y), 0.5f * (Z1n.x - Z1j.x));
    float2 W0 = cmul(D0, K0);
    float2 W1 = cmul(D1, K1);
    A[sJ * ROWP + kJ] = make_float2(W0.x - W1.y, W0.y + W1.x);
    A[sN * ROWP + kN] = make_float2(W0.x + W1.y, W1.x - W0.y);
}

// ---- fused row pass (R6-verbatim): fwd radix-4 DIF (8 rows) -> pw -> inv DIT (4 rows) ----
__global__ void k_rowpw(float2* __restrict__ C) {
    __shared__ float2 A[8 * ROWP];
    __shared__ float2 tw[192];
    int t = threadIdx.x;
    int p = blockIdx.x >> 6;
    int g = blockIdx.x & 63;
    int rows[4];
    if (g == 0) { rows[0] = 0; rows[1] = 1; rows[2] = 128; rows[3] = 255; }
    else        { rows[0] = 2 * g; rows[1] = 2 * g + 1; rows[2] = 256 - 2 * g; rows[3] = 255 - 2 * g; }
    if (t < 192) {
        float sv, cv;
        __sincosf(-TWO_PI * (float)t * (1.0f / 256.0f), &sv, &cv);
        tw[t] = make_float2(cv, sv);
    }
    float2* b0 = C + (size_t)(2 * p) * L;
    float2* b1 = b0 + L;
    for (int u = t; u < 1024; u += 256) {
        int slot = u >> 7;
        int f = (u & 127) << 1;
        const float2* arr = (slot < 4) ? b0 : b1;
        int grow = dr4(rows[slot & 3]);
        float4 v = *(const float4*)(arr + (grow << 8) + f);
        *(float4*)&A[slot * ROWP + f] = v;
    }
    __syncthreads();
#pragma unroll
    for (int lm = 8; lm >= 6; lm -= 2) {
        int Q = 1 << (lm - 2), f = 256 >> lm;
        for (int u = t; u < 512; u += 256) {
            int row = u >> 6, qi = u & 63;
            int q = qi & (Q - 1);
            int i0 = ((qi - q) << 2) + q;
            bfly4_fwd(A, row * ROWP + i0, Q, tw, f, q);
        }
        __syncthreads();
    }
#pragma unroll
    for (int lm = 4; lm >= 2; lm -= 2) {
        int Q = 1 << (lm - 2), f = 256 >> lm;
        for (int u = t; u < 512; u += 256) {
            int row = u & 7, qi = u >> 3;
            int q = qi & (Q - 1);
            int i0 = ((qi - q) << 2) + q;
            bfly4_fwd(A, row * ROWP + i0, Q, tw, f, q);
        }
        __syncthreads();
    }
    if (g) {
        pw_unit(A, 0, t, 2, 255 - t);
    } else {
        if (t == 0)      { pw_unit(A, 0, 0, 0, 0); pw_unit(A, 0, 2, 0, 2); }
        else if (t < 128) pw_unit(A, 0, dr4(t), 0, dr4(256 - t));
        else              { int qq = t - 128; pw_unit(A, 2, qq, 2, 255 - qq); }
    }
    pw_unit(A, 1, t, 3, 255 - t);
    __syncthreads();
#pragma unroll
    for (int lm = 2; lm <= 4; lm += 2) {
        int Q = 1 << (lm - 2), f = 256 >> lm;
        int row = t & 3, qi = t >> 2;
        int q = qi & (Q - 1);
        int i0 = ((qi - q) << 2) + q;
        bfly4_inv(A, row * ROWP + i0, Q, tw, f, q);
        __syncthreads();
    }
#pragma unroll
    for (int lm = 6; lm <= 8; lm += 2) {
        int Q = 1 << (lm - 2), f = 256 >> lm;
        int row = t >> 6, qi = t & 63;
        int q = qi & (Q - 1);
        int i0 = ((qi - q) << 2) + q;
        bfly4_inv(A, row * ROWP + i0, Q, tw, f, q);
        __syncthreads();
    }
    for (int u = t; u < 512; u += 256) {
        int slot = u >> 7;
        int f = (u & 127) << 1;
        int r = rows[slot];
        float2 va = A[slot * ROWP + f];
        float2 vb = A[slot * ROWP + f + 1];
        int pha = (f * r) & (L - 1);
        int phb = ((f + 1) * r) & (L - 1);
        float sa, ca, sb, cb2;
        __sincosf(TWO_PI * (float)pha * INV_L, &sa, &ca);
        __sincosf(TWO_PI * (float)phb * INV_L, &sb, &cb2);
        float2 ra = cmul(va, make_float2(ca, sa));
        float2 rb = cmul(vb, make_float2(cb2, sb));
        *(float4*)(b0 + (dr4(r) << 8) + f) = make_float4(ra.x, ra.y, rb.x, rb.y);
    }
}

// ---- inverse col pass; 128 threads, 8 columns; fused mix + partial max ----
__global__ __launch_bounds__(128) void k_colinv(const float2* __restrict__ C,
                                                const float* __restrict__ dryf,
                                                const float* __restrict__ mixv,
                                                float* __restrict__ out,
                                                float* __restrict__ partial) {
    __shared__ float2 T[128 * TP2];
    __shared__ float2 tw[256];
    __shared__ float sm0[2], sm1[2];
    int t = threadIdx.x;
    int a = blockIdx.x >> 5;       // pair
    int cg = blockIdx.x & 31;
    int c0 = cg * 8;
    const float2* base = C + (size_t)(2 * a) * L;
    for (int i = t; i < 256; i += 128) {
        float sv, cv;
        __sincosf(-TWO_PI * (float)i * (1.0f / 256.0f), &sv, &cv);
        tw[i] = make_float2(cv, sv);
    }
    int j = t >> 3, c = t & 7;
    int n1 = c0 + c;
    float2 r[16];
#pragma unroll
    for (int jj = 0; jj < 16; jj++) r[jj] = base[n1 + ((jj + 16 * j) << 8)];
    __syncthreads();
#pragma unroll
    for (int h = 0; h < 4; h++) bf4i(r[4 * h], r[4 * h + 1], r[4 * h + 2], r[4 * h + 3], tw, 64, 0);
#pragma unroll
    for (int q = 0; q < 4; q++) bf4i(r[q], r[q + 4], r[q + 8], r[q + 12], tw, 16, q);
    float2 r2[16];
    if (j < 8) {
#pragma unroll
        for (int jj = 0; jj < 16; jj++) T[(jj + 16 * j) * TP2 + c] = r[jj];
    }
    __syncthreads();
#pragma unroll
    for (int m = 0; m < 8; m++) r2[m] = T[(j + 16 * m) * TP2 + c];
    __syncthreads();
    if (j >= 8) {
#pragma unroll
        for (int jj = 0; jj < 16; jj++) T[(16 * (j - 8) + jj) * TP2 + c] = r[jj];
    }
    __syncthreads();
#pragma unroll
    for (int m = 8; m < 16; m++) r2[m] = T[(j + 16 * (m - 8)) * TP2 + c];
#pragma unroll
    for (int h = 0; h < 4; h++) bf4i(r2[4 * h], r2[4 * h + 1], r2[4 * h + 2], r2[4 * h + 3], tw, 4, j);
#pragma unroll
    for (int m0 = 0; m0 < 4; m0++) bf4i(r2[m0], r2[m0 + 4], r2[m0 + 8], r2[m0 + 12], tw, 1, j + 16 * m0);
    int b0 = 2 * a, b1 = 2 * a + 1;
    float mix0 = mixv[b0], mix1 = mixv[b1];
    float om0 = 1.f - mix0, om1 = 1.f - mix1;
    const float* dry0 = dryf + (size_t)b0 * N_T;
    const float* dry1 = dryf + (size_t)b1 * N_T;
    float* out0 = out + (size_t)b0 * N_T;
    float* out1 = out + (size_t)b1 * N_T;
    float m0 = -3.4e38f, m1 = -3.4e38f;
#pragma unroll
    for (int m = 0; m < 8; m++) {
        int pos = n1 + ((j + 16 * m) << 8);      // n2 = j+16m < 128
        float d0 = dry0[pos], d1 = dry1[pos];
        float o0 = mix0 * (r2[m].x * INV_L) + om0 * d0;
        float o1 = mix1 * (r2[m].y * INV_L) + om1 * d1;
        out0[pos] = o0;
        out1[pos] = o1;
        m0 = fmaxf(m0, o0);
        m1 = fmaxf(m1, o1);
    }
#pragma unroll
    for (int off = 32; off > 0; off >>= 1) {
        m0 = fmaxf(m0, __shfl_down(m0, off));
        m1 = fmaxf(m1, __shfl_down(m1, off));
    }
    if ((t & 63) == 0) { sm0[t >> 6] = m0; sm1[t >> 6] = m1; }
    __syncthreads();
    if (t == 0) {
        partial[b0 * 32 + cg] = fmaxf(sm0[0], sm0[1]);
        partial[b1 * 32 + cg] = fmaxf(sm1[0], sm1[1]);
    }
}

__global__ void k_norm(float* __restrict__ out, const float* __restrict__ partial) {
    int blk = blockIdx.x;
    int b = blk >> 5;
    int ch = blk & 31;
    __shared__ float smx;
    if (threadIdx.x < 32) {
        float p = partial[b * 32 + threadIdx.x];
#pragma unroll
        for (int off = 16; off > 0; off >>= 1) p = fmaxf(p, __shfl_down(p, off, 32));
        if (threadIdx.x == 0) smx = p;
    }
    __syncthreads();
    float inv = 1.f / (smx + 1e-8f);
    size_t base = (size_t)b * N_T + ch * 1024 + threadIdx.x * 4;
    float4 o = *(const float4*)(out + base);
    o.x *= inv; o.y *= inv; o.z *= inv; o.w *= inv;
    *(float4*)(out + base) = o;
}

extern "C" void kernel_launch(void* const* d_in, const int* in_sizes, int n_in,
                              void* d_out, int out_size, void* d_ws, size_t ws_size,
                              hipStream_t stream) {
    const float* events = (const float*)d_in[0];
    const int* indices = (const int*)d_in[1];
    const float* g      = (const float*)d_in[2];
    const float* rooms  = (const float*)d_in[3];
    const float* w_room = (const float*)d_in[4];
    const float* b_room = (const float*)d_in[5];
    const float* w_mix  = (const float*)d_in[6];
    const float* b_mix  = (const float*)d_in[7];
    float* out = (float*)d_out;

    char* ws = (char*)d_ws;
    float2* C = (float2*)ws;  // [64][65536] complex: Z_b = dry_b + i*K_b (spectral)
    size_t off = (size_t)BATCH * L * sizeof(float2);
    float* dryf = (float*)(ws + off);
    off += (size_t)BATCH * N_T * sizeof(float);
    float* wroom = (float*)(ws + off);
    off += BATCH * NROOM * sizeof(float);
    float* mixv = (float*)(ws + off);
    off += BATCH * sizeof(float);
    float* partial = (float*)(ws + off);

    k_prep<<<1, 64, 0, stream>>>(g, w_room, b_room, w_mix, b_mix, wroom, mixv);
    k_fwd<<<BATCH * 32, 128, 0, stream>>>(events, indices, rooms, wroom, dryf, C);
    k_rowpw<<<NPAIR * 64, 256, 0, stream>>>(C);
    k_colinv<<<NPAIR * 32, 128, 0, stream>>>(C, dryf, mixv, out, partial);
    k_norm<<<BATCH * 32, 256, 0, stream>>>(out, partial);
}

// Round 13
// 86.510 us; speedup vs baseline: 1.2981x; 1.2981x over previous
//
#include <hip/hip_runtime.h>
#include <math.h>

#define N_T 32768
#define L 65536
#define BATCH 64
#define NPAIR 32
#define NEV 8
#define NROOM 16
#define ROWP 258
#define TP 17
#define TWO_PI 6.2831853071795864769f
#define INV_L (1.0f / 65536.0f)

typedef float __attribute__((ext_vector_type(4))) nfloat4;   // native vec for nontemporal builtin

__device__ __forceinline__ float2 cmul(float2 a, float2 b) {
    return make_float2(a.x * b.x - a.y * b.y, a.x * b.y + a.y * b.x);
}
// base-4 digit reversal of an 8-bit index (involution)
__device__ __forceinline__ int dr4(int p) {
    return ((p & 3) << 6) | ((p & 12) << 2) | ((p & 48) >> 2) | ((p & 192) >> 6);
}

// register radix-4 DIF butterfly (fwd)
__device__ __forceinline__ void bf4f(float2& a, float2& b, float2& c, float2& d,
                                     const float2* tw, int f, int q) {
    float2 t0 = make_float2(a.x + c.x, a.y + c.y);
    float2 t1 = make_float2(a.x - c.x, a.y - c.y);
    float2 t2 = make_float2(b.x + d.x, b.y + d.y);
    float2 u  = make_float2(b.x - d.x, b.y - d.y);
    float2 t3 = make_float2(u.y, -u.x);            // -i*u
    a = make_float2(t0.x + t2.x, t0.y + t2.y);
    b = cmul(make_float2(t1.x + t3.x, t1.y + t3.y), tw[f * q]);
    c = cmul(make_float2(t0.x - t2.x, t0.y - t2.y), tw[2 * f * q]);
    d = cmul(make_float2(t1.x - t3.x, t1.y - t3.y), tw[3 * f * q]);
}
// register radix-4 DIT butterfly (inv): exact inverse of bf4f
__device__ __forceinline__ void bf4i(float2& a, float2& b, float2& c, float2& d,
                                     const float2* tw, int f, int q) {
    float2 w1 = tw[f * q], w2 = tw[2 * f * q], w3 = tw[3 * f * q];
    float2 y0 = a;
    float2 y1 = cmul(b, make_float2(w1.x, -w1.y));
    float2 y2 = cmul(c, make_float2(w2.x, -w2.y));
    float2 y3 = cmul(d, make_float2(w3.x, -w3.y));
    float2 t0 = make_float2(y0.x + y2.x, y0.y + y2.y);
    float2 t2 = make_float2(y0.x - y2.x, y0.y - y2.y);
    float2 t1 = make_float2(y1.x + y3.x, y1.y + y3.y);
    float2 u  = make_float2(y1.x - y3.x, y1.y - y3.y);
    a = make_float2(t0.x + t1.x, t0.y + t1.y);
    b = make_float2(t2.x - u.y, t2.y + u.x);
    c = make_float2(t0.x - t1.x, t0.y - t1.y);
    d = make_float2(t2.x + u.y, t2.y - u.x);
}
__device__ __forceinline__ void bfly4_fwd(float2* A, int a0, int st, const float2* tw, int f, int q) {
    bf4f(A[a0], A[a0 + st], A[a0 + 2 * st], A[a0 + 3 * st], tw, f, q);
}
__device__ __forceinline__ void bfly4_inv(float2* A, int a0, int st, const float2* tw, int f, int q) {
    bf4i(A[a0], A[a0 + st], A[a0 + 2 * st], A[a0 + 3 * st], tw, f, q);
}

// ---- gating ----
__global__ void k_prep(const float* __restrict__ g, const float* __restrict__ w_room,
                       const float* __restrict__ b_room, const float* __restrict__ w_mix,
                       const float* __restrict__ b_mix,
                       float* __restrict__ wroom, float* __restrict__ mixv) {
    int b = threadIdx.x;
    if (b >= BATCH) return;
    float logits[NROOM];
    for (int r = 0; r < NROOM; r++) logits[r] = b_room[r];
    float acc_mix = b_mix[0];
    for (int d = 0; d < 128; d++) {
        float gv = g[b * 128 + d];
        for (int r = 0; r < NROOM; r++) logits[r] += gv * w_room[d * NROOM + r];
        acc_mix += gv * w_mix[d];
    }
    float m = logits[0];
    for (int r = 1; r < NROOM; r++) m = fmaxf(m, logits[r]);
    float s = 0.f;
    for (int r = 0; r < NROOM; r++) { logits[r] = expf(logits[r] - m); s += logits[r]; }
    float inv = 1.f / s;
    for (int r = 0; r < NROOM; r++) wroom[b * NROOM + r] = logits[r] * inv;
    mixv[b] = 1.f / (1.f + expf(-acc_mix));
}

// ---- fused: build dry+K tile, write dryf, register radix-4 fwd col FFT + big twiddle ----
// XCD-affine: bid = i*8 + x; batch b = 2*(x + 8*(lb>>1)) + (lb&1) so (b>>1)%8 == x.
__global__ void k_fwd(const float* __restrict__ events, const int* __restrict__ indices,
                      const float* __restrict__ rooms, const float* __restrict__ wroom,
                      float* __restrict__ dryf, float2* __restrict__ C) {
    __shared__ float2 T[256 * TP];       // transpose buffer; front 16 KB reused as staging
    __shared__ float2 tw[256];
    __shared__ float2 fine[256];
    int t = threadIdx.x;
    int x = blockIdx.x & 7;
    int i = blockIdx.x >> 3;             // 0..127
    int cg = i & 15;
    int lb = i >> 4;                     // 0..7
    int pair = x + 8 * (lb >> 1);
    int a = 2 * pair + (lb & 1);         // batch
    int c0 = cg * 16;                    // column group
    float2* base = C + (size_t)a * L;
    {
        float sv, cv;
        __sincosf(-TWO_PI * (float)t * (1.0f / 256.0f), &sv, &cv);
        tw[t] = make_float2(cv, sv);
        __sincosf(-TWO_PI * (float)t * INV_L, &sv, &cv);
        fine[t] = make_float2(cv, sv);
    }
    float* dtile = (float*)T;            // [128][16] dry
    float* ktile = dtile + 128 * 16;     // [128][16] K
    const float* eb = events + (size_t)a * NEV * N_T;
    const int* ib = indices + a * NEV;
    const float* wb = wroom + a * NROOM;
    // unit u = n2*4 + qc (qc = float4-column); thread owns u and u+256
    int n2a = t >> 2, qa = (t & 3) << 2;
    int n2b = n2a + 64;
    float4 d0 = make_float4(0.f, 0.f, 0.f, 0.f), d1 = d0;
#pragma unroll
    for (int e = 0; e < NEV; e++) {
        int s = ib[e];
        const float* er = eb + e * N_T + c0;
        if (n2a >= s) {
            nfloat4 v = __builtin_nontemporal_load((const nfloat4*)(er + qa + ((n2a - s) << 8)));
            d0.x += v.x; d0.y += v.y; d0.z += v.z; d0.w += v.w;
        }
        if (n2b >= s) {
            nfloat4 v = __builtin_nontemporal_load((const nfloat4*)(er + qa + ((n2b - s) << 8)));
            d1.x += v.x; d1.y += v.y; d1.z += v.z; d1.w += v.w;
        }
    }
    float4 k0 = make_float4(0.f, 0.f, 0.f, 0.f), k1 = k0;
#pragma unroll
    for (int r = 0; r < NROOM; r++) {
        float w = wb[r];
        const float* rr = rooms + (size_t)r * N_T + c0;
        float4 v0 = *(const float4*)(rr + qa + (n2a << 8));
        float4 v1 = *(const float4*)(rr + qa + (n2b << 8));
        k0.x += w * v0.x; k0.y += w * v0.y; k0.z += w * v0.z; k0.w += w * v0.w;
        k1.x += w * v1.x; k1.y += w * v1.y; k1.z += w * v1.z; k1.w += w * v1.w;
    }
    float* db = dryf + (size_t)a * N_T + c0;
    *(float4*)(db + qa + (n2a << 8)) = d0;
    *(float4*)(db + qa + (n2b << 8)) = d1;
    *(float4*)&dtile[n2a * 16 + qa] = d0;
    *(float4*)&dtile[n2b * 16 + qa] = d1;
    *(float4*)&ktile[n2a * 16 + qa] = k0;
    *(float4*)&ktile[n2b * 16 + qa] = k1;
    __syncthreads();
    int j = t >> 4, c = t & 15;
    int n1 = c0 + c;
    float2 r[16];
#pragma unroll
    for (int m = 0; m < 8; m++) {
        int n2 = j + 16 * m;             // < 128 always (j<16, m<8)
        r[m] = make_float2(dtile[n2 * 16 + c], ktile[n2 * 16 + c]);
    }
#pragma unroll
    for (int m = 8; m < 16; m++) r[m] = make_float2(0.f, 0.f);
    // stages 1-2 in registers
#pragma unroll
    for (int m0 = 0; m0 < 4; m0++) bf4f(r[m0], r[m0 + 4], r[m0 + 8], r[m0 + 12], tw, 1, j + 16 * m0);
#pragma unroll
    for (int h = 0; h < 4; h++) bf4f(r[4 * h], r[4 * h + 1], r[4 * h + 2], r[4 * h + 3], tw, 4, j);
    __syncthreads();                     // staging region dead; safe to overwrite T
#pragma unroll
    for (int m = 0; m < 16; m++) T[(j + 16 * m) * TP + c] = r[m];
    __syncthreads();
#pragma unroll
    for (int jj = 0; jj < 16; jj++) r[jj] = T[(jj + 16 * j) * TP + c];
#pragma unroll
    for (int q = 0; q < 4; q++) bf4f(r[q], r[q + 4], r[q + 8], r[q + 12], tw, 16, q);
#pragma unroll
    for (int h = 0; h < 4; h++) bf4f(r[4 * h], r[4 * h + 1], r[4 * h + 2], r[4 * h + 3], tw, 64, 0);
#pragma unroll
    for (int jj = 0; jj < 16; jj++) {
        int p = jj + 16 * j;
        int k2 = dr4(p);
        int ph = (n1 * k2) & (L - 1);
        float2 w = cmul(tw[ph >> 8], fine[ph & 255]);
        base[n1 + (p << 8)] = cmul(r[jj], w);
    }
}

// ---- pointwise unit (LDS form) ----
__device__ __forceinline__ void pw_unit(float2* A, int sJ, int kJ, int sN, int kN) {
    float2 Z0j = A[sJ * ROWP + kJ],       Z0n = A[sN * ROWP + kN];
    float2 Z1j = A[(4 + sJ) * ROWP + kJ], Z1n = A[(4 + sN) * ROWP + kN];
    float2 D0 = make_float2(0.5f * (Z0j.x + Z0n.x), 0.5f * (Z0j.y - Z0n.y));
    float2 K0 = make_float2(0.5f * (Z0j.y + Z0n.y), 0.5f * (Z0n.x - Z0j.x));
    float2 D1 = make_float2(0.5f * (Z1j.x + Z1n.x), 0.5f * (Z1j.y - Z1n.y));
    float2 K1 = make_float2(0.5f * (Z1j.y + Z1n.y), 0.5f * (Z1n.x - Z1j.x));
    float2 W0 = cmul(D0, K0);
    float2 W1 = cmul(D1, K1);
    A[sJ * ROWP + kJ] = make_float2(W0.x - W1.y, W0.y + W1.x);
    A[sN * ROWP + kN] = make_float2(W0.x + W1.y, W1.x - W0.y);
}

// ---- fused row pass: fwd radix-4 DIF (8 rows) -> pointwise -> inv DIT (4 rows) ----
// XCD-affine: bid = i*8 + x; pair = x + 8*(i>>6); g = i&63.
__global__ void k_rowpw(float2* __restrict__ C) {
    __shared__ float2 A[8 * ROWP];
    __shared__ float2 tw[192];
    int t = threadIdx.x;
    int x = blockIdx.x & 7;
    int i = blockIdx.x >> 3;           // 0..255
    int g = i & 63;
    int p = x + 8 * (i >> 6);          // pair
    int rows[4];
    if (g == 0) { rows[0] = 0; rows[1] = 1; rows[2] = 128; rows[3] = 255; }
    else        { rows[0] = 2 * g; rows[1] = 2 * g + 1; rows[2] = 256 - 2 * g; rows[3] = 255 - 2 * g; }
    if (t < 192) {
        float sv, cv;
        __sincosf(-TWO_PI * (float)t * (1.0f / 256.0f), &sv, &cv);
        tw[t] = make_float2(cv, sv);
    }
    float2* b0 = C + (size_t)(2 * p) * L;
    float2* b1 = b0 + L;
    for (int u = t; u < 1024; u += 256) {
        int slot = u >> 7;
        int f = (u & 127) << 1;
        const float2* arr = (slot < 4) ? b0 : b1;
        int grow = dr4(rows[slot & 3]);
        float4 v = *(const float4*)(arr + (grow << 8) + f);
        *(float4*)&A[slot * ROWP + f] = v;
    }
    __syncthreads();
#pragma unroll
    for (int lm = 8; lm >= 6; lm -= 2) {
        int Q = 1 << (lm - 2), f = 256 >> lm;
        for (int u = t; u < 512; u += 256) {
            int row = u >> 6, qi = u & 63;
            int q = qi & (Q - 1);
            int i0 = ((qi - q) << 2) + q;
            bfly4_fwd(A, row * ROWP + i0, Q, tw, f, q);
        }
        __syncthreads();
    }
#pragma unroll
    for (int lm = 4; lm >= 2; lm -= 2) {
        int Q = 1 << (lm - 2), f = 256 >> lm;
        for (int u = t; u < 512; u += 256) {
            int row = u & 7, qi = u >> 3;
            int q = qi & (Q - 1);
            int i0 = ((qi - q) << 2) + q;
            bfly4_fwd(A, row * ROWP + i0, Q, tw, f, q);
        }
        __syncthreads();
    }
    if (g) {
        pw_unit(A, 0, t, 2, 255 - t);
    } else {
        if (t == 0)      { pw_unit(A, 0, 0, 0, 0); pw_unit(A, 0, 2, 0, 2); }
        else if (t < 128) pw_unit(A, 0, dr4(t), 0, dr4(256 - t));
        else              { int qq = t - 128; pw_unit(A, 2, qq, 2, 255 - qq); }
    }
    pw_unit(A, 1, t, 3, 255 - t);
    __syncthreads();
#pragma unroll
    for (int lm = 2; lm <= 4; lm += 2) {
        int Q = 1 << (lm - 2), f = 256 >> lm;
        int row = t & 3, qi = t >> 2;
        int q = qi & (Q - 1);
        int i0 = ((qi - q) << 2) + q;
        bfly4_inv(A, row * ROWP + i0, Q, tw, f, q);
        __syncthreads();
    }
#pragma unroll
    for (int lm = 6; lm <= 8; lm += 2) {
        int Q = 1 << (lm - 2), f = 256 >> lm;
        int row = t >> 6, qi = t & 63;
        int q = qi & (Q - 1);
        int i0 = ((qi - q) << 2) + q;
        bfly4_inv(A, row * ROWP + i0, Q, tw, f, q);
        __syncthreads();
    }
    for (int u = t; u < 512; u += 256) {
        int slot = u >> 7;
        int f = (u & 127) << 1;
        int r = rows[slot];
        float2 va = A[slot * ROWP + f];
        float2 vb = A[slot * ROWP + f + 1];
        int pha = (f * r) & (L - 1);
        int phb = ((f + 1) * r) & (L - 1);
        float sa, ca, sb, cb2;
        __sincosf(TWO_PI * (float)pha * INV_L, &sa, &ca);
        __sincosf(TWO_PI * (float)phb * INV_L, &sb, &cb2);
        float2 ra = cmul(va, make_float2(ca, sa));
        float2 rb = cmul(vb, make_float2(cb2, sb));
        *(float4*)(b0 + (dr4(r) << 8) + f) = make_float4(ra.x, ra.y, rb.x, rb.y);
    }
}

// ---- inverse col pass (register): stages 1,4 | transpose | 16,64; fused mix+max ----
// XCD-affine: bid = i*8 + x; pair = x + 8*(i>>4); cbg = i&15.
__global__ void k_fft_col_inv(float2* __restrict__ C, const float* __restrict__ dryf,
                              const float* __restrict__ mixv, float* __restrict__ out,
                              float* __restrict__ partial) {
    __shared__ float2 T[256 * TP];
    __shared__ float2 tw[256];
    __shared__ float sm0[4], sm1[4];
    int t = threadIdx.x;
    int x = blockIdx.x & 7;
    int i = blockIdx.x >> 3;       // 0..63
    int cbg = i & 15;
    int a = x + 8 * (i >> 4);      // pair
    int c0 = cbg * 16;
    float2* base = C + (size_t)(2 * a) * L;
    {
        float sv, cv;
        __sincosf(-TWO_PI * (float)t * (1.0f / 256.0f), &sv, &cv);
        tw[t] = make_float2(cv, sv);
    }
    int j = t >> 4, c = t & 15;
    int n1 = c0 + c;
    float2 r[16];
#pragma unroll
    for (int jj = 0; jj < 16; jj++) r[jj] = base[n1 + ((jj + 16 * j) << 8)];
    __syncthreads();
#pragma unroll
    for (int h = 0; h < 4; h++) bf4i(r[4 * h], r[4 * h + 1], r[4 * h + 2], r[4 * h + 3], tw, 64, 0);
#pragma unroll
    for (int q = 0; q < 4; q++) bf4i(r[q], r[q + 4], r[q + 8], r[q + 12], tw, 16, q);
#pragma unroll
    for (int jj = 0; jj < 16; jj++) T[(jj + 16 * j) * TP + c] = r[jj];
    __syncthreads();
#pragma unroll
    for (int m = 0; m < 16; m++) r[m] = T[(j + 16 * m) * TP + c];
#pragma unroll
    for (int h = 0; h < 4; h++) bf4i(r[4 * h], r[4 * h + 1], r[4 * h + 2], r[4 * h + 3], tw, 4, j);
#pragma unroll
    for (int m0 = 0; m0 < 4; m0++) bf4i(r[m0], r[m0 + 4], r[m0 + 8], r[m0 + 12], tw, 1, j + 16 * m0);
    int b0 = 2 * a, b1 = 2 * a + 1;
    float mix0 = mixv[b0], mix1 = mixv[b1];
    float om0 = 1.f - mix0, om1 = 1.f - mix1;
    const float* dry0 = dryf + (size_t)b0 * N_T;
    const float* dry1 = dryf + (size_t)b1 * N_T;
    float* out0 = out + (size_t)b0 * N_T;
    float* out1 = out + (size_t)b1 * N_T;
    float m0 = -3.4e38f, m1 = -3.4e38f;
#pragma unroll
    for (int m = 0; m < 8; m++) {
        int pos = n1 + ((j + 16 * m) << 8);
        float d0 = dry0[pos], d1 = dry1[pos];
        float o0 = mix0 * (r[m].x * INV_L) + om0 * d0;
        float o1 = mix1 * (r[m].y * INV_L) + om1 * d1;
        out0[pos] = o0;
        out1[pos] = o1;
        m0 = fmaxf(m0, o0);
        m1 = fmaxf(m1, o1);
    }
#pragma unroll
    for (int off = 32; off > 0; off >>= 1) {
        m0 = fmaxf(m0, __shfl_down(m0, off));
        m1 = fmaxf(m1, __shfl_down(m1, off));
    }
    if ((t & 63) == 0) { sm0[t >> 6] = m0; sm1[t >> 6] = m1; }
    __syncthreads();
    if (t == 0) {
        partial[b0 * 16 + cbg] = fmaxf(fmaxf(sm0[0], sm0[1]), fmaxf(sm0[2], sm0[3]));
        partial[b1 * 16 + cbg] = fmaxf(fmaxf(sm1[0], sm1[1]), fmaxf(sm1[2], sm1[3]));
    }
}

__global__ void k_norm(float* __restrict__ out, const float* __restrict__ partial) {
    int blk = blockIdx.x;
    int b = blk >> 5;
    int ch = blk & 31;
    __shared__ float smx;
    if (threadIdx.x < 16) {
        float p = partial[b * 16 + threadIdx.x];
#pragma unroll
        for (int off = 8; off > 0; off >>= 1) p = fmaxf(p, __shfl_down(p, off, 16));
        if (threadIdx.x == 0) smx = p;
    }
    __syncthreads();
    float inv = 1.f / (smx + 1e-8f);
    size_t base = (size_t)b * N_T + ch * 1024 + threadIdx.x * 4;
    float4 o = *(const float4*)(out + base);
    o.x *= inv; o.y *= inv; o.z *= inv; o.w *= inv;
    *(float4*)(out + base) = o;
}

extern "C" void kernel_launch(void* const* d_in, const int* in_sizes, int n_in,
                              void* d_out, int out_size, void* d_ws, size_t ws_size,
                              hipStream_t stream) {
    const float* events = (const float*)d_in[0];
    const int* indices = (const int*)d_in[1];
    const float* g      = (const float*)d_in[2];
    const float* rooms  = (const float*)d_in[3];
    const float* w_room = (const float*)d_in[4];
    const float* b_room = (const float*)d_in[5];
    const float* w_mix  = (const float*)d_in[6];
    const float* b_mix  = (const float*)d_in[7];
    float* out = (float*)d_out;

    char* ws = (char*)d_ws;
    float2* C = (float2*)ws;  // [64][65536] complex: Z_b = dry_b + i*K_b (spectral)
    size_t off = (size_t)BATCH * L * sizeof(float2);
    float* dryf = (float*)(ws + off);
    off += (size_t)BATCH * N_T * sizeof(float);
    float* wroom = (float*)(ws + off);
    off += BATCH * NROOM * sizeof(float);
    float* mixv = (float*)(ws + off);
    off += BATCH * sizeof(float);
    float* partial = (float*)(ws + off);

    k_prep<<<1, 64, 0, stream>>>(g, w_room, b_room, w_mix, b_mix, wroom, mixv);
    k_fwd<<<BATCH * 16, 256, 0, stream>>>(events, indices, rooms, wroom, dryf, C);
    k_rowpw<<<NPAIR * 64, 256, 0, stream>>>(C);
    k_fft_col_inv<<<NPAIR * 16, 256, 0, stream>>>(C, dryf, mixv, out, partial);
    k_norm<<<BATCH * 32, 256, 0, stream>>>(out, partial);
}

// Round 14
// 75.976 us; speedup vs baseline: 1.4781x; 1.1386x over previous
//
#include <hip/hip_runtime.h>
#include <math.h>

#define N_T 32768
#define L 65536
#define BATCH 64
#define NPAIR 32
#define NEV 8
#define NROOM 16
#define ROWP 258
#define TWP 65                 // k_fwd transpose pad (64 cols)
#define TWP2 33                // colinv transpose pad (32 cols)
#define TWO_PI 6.2831853071795864769f
#define INV_L (1.0f / 65536.0f)

__device__ __forceinline__ float2 cmul(float2 a, float2 b) {
    return make_float2(a.x * b.x - a.y * b.y, a.x * b.y + a.y * b.x);
}
// base-4 digit reversal of an 8-bit index (involution)
__device__ __forceinline__ int dr4(int p) {
    return ((p & 3) << 6) | ((p & 12) << 2) | ((p & 48) >> 2) | ((p & 192) >> 6);
}

// register radix-4 DIF butterfly (fwd)
__device__ __forceinline__ void bf4f(float2& a, float2& b, float2& c, float2& d,
                                     const float2* tw, int f, int q) {
    float2 t0 = make_float2(a.x + c.x, a.y + c.y);
    float2 t1 = make_float2(a.x - c.x, a.y - c.y);
    float2 t2 = make_float2(b.x + d.x, b.y + d.y);
    float2 u  = make_float2(b.x - d.x, b.y - d.y);
    float2 t3 = make_float2(u.y, -u.x);            // -i*u
    a = make_float2(t0.x + t2.x, t0.y + t2.y);
    b = cmul(make_float2(t1.x + t3.x, t1.y + t3.y), tw[f * q]);
    c = cmul(make_float2(t0.x - t2.x, t0.y - t2.y), tw[2 * f * q]);
    d = cmul(make_float2(t1.x - t3.x, t1.y - t3.y), tw[3 * f * q]);
}
// register radix-4 DIT butterfly (inv): exact inverse of bf4f
__device__ __forceinline__ void bf4i(float2& a, float2& b, float2& c, float2& d,
                                     const float2* tw, int f, int q) {
    float2 w1 = tw[f * q], w2 = tw[2 * f * q], w3 = tw[3 * f * q];
    float2 y0 = a;
    float2 y1 = cmul(b, make_float2(w1.x, -w1.y));
    float2 y2 = cmul(c, make_float2(w2.x, -w2.y));
    float2 y3 = cmul(d, make_float2(w3.x, -w3.y));
    float2 t0 = make_float2(y0.x + y2.x, y0.y + y2.y);
    float2 t2 = make_float2(y0.x - y2.x, y0.y - y2.y);
    float2 t1 = make_float2(y1.x + y3.x, y1.y + y3.y);
    float2 u  = make_float2(y1.x - y3.x, y1.y - y3.y);
    a = make_float2(t0.x + t1.x, t0.y + t1.y);
    b = make_float2(t2.x - u.y, t2.y + u.x);
    c = make_float2(t0.x - t1.x, t0.y - t1.y);
    d = make_float2(t2.x + u.y, t2.y - u.x);
}
__device__ __forceinline__ void bfly4_fwd(float2* A, int a0, int st, const float2* tw, int f, int q) {
    bf4f(A[a0], A[a0 + st], A[a0 + 2 * st], A[a0 + 3 * st], tw, f, q);
}
__device__ __forceinline__ void bfly4_inv(float2* A, int a0, int st, const float2* tw, int f, int q) {
    bf4i(A[a0], A[a0 + st], A[a0 + 2 * st], A[a0 + 3 * st], tw, f, q);
}

// ---- gating ----
__global__ void k_prep(const float* __restrict__ g, const float* __restrict__ w_room,
                       const float* __restrict__ b_room, const float* __restrict__ w_mix,
                       const float* __restrict__ b_mix,
                       float* __restrict__ wroom, float* __restrict__ mixv) {
    int b = threadIdx.x;
    if (b >= BATCH) return;
    float logits[NROOM];
    for (int r = 0; r < NROOM; r++) logits[r] = b_room[r];
    float acc_mix = b_mix[0];
    for (int d = 0; d < 128; d++) {
        float gv = g[b * 128 + d];
        for (int r = 0; r < NROOM; r++) logits[r] += gv * w_room[d * NROOM + r];
        acc_mix += gv * w_mix[d];
    }
    float m = logits[0];
    for (int r = 1; r < NROOM; r++) m = fmaxf(m, logits[r]);
    float s = 0.f;
    for (int r = 0; r < NROOM; r++) { logits[r] = expf(logits[r] - m); s += logits[r]; }
    float inv = 1.f / s;
    for (int r = 0; r < NROOM; r++) wroom[b * NROOM + r] = logits[r] * inv;
    mixv[b] = 1.f / (1.f + expf(-acc_mix));
}

// ---- fused wide col pass: stage dry+K (64 cols), write dryf, radix-4 fwd FFT, big twiddle ----
// 1024 threads, 64 columns/block: C writes are 512B contiguous per wave instruction.
__global__ __launch_bounds__(1024) void k_fwd(const float* __restrict__ events,
                                              const int* __restrict__ indices,
                                              const float* __restrict__ rooms,
                                              const float* __restrict__ wroom,
                                              float* __restrict__ dryf, float2* __restrict__ C) {
    __shared__ float2 T[128 * TWP];      // 66.5 KB; front 64 KB doubles as dry/K staging
    __shared__ float2 tw[256];
    __shared__ float2 fine[256];
    int t = threadIdx.x;
    int a = blockIdx.x >> 2;             // batch
    int cg = blockIdx.x & 3;             // column group (4 x 64)
    int c0 = cg * 64;
    float2* base = C + (size_t)a * L;
    if (t < 256) {
        float sv, cv;
        __sincosf(-TWO_PI * (float)t * (1.0f / 256.0f), &sv, &cv);
        tw[t] = make_float2(cv, sv);
        __sincosf(-TWO_PI * (float)t * INV_L, &sv, &cv);
        fine[t] = make_float2(cv, sv);
    }
    float* dtile = (float*)T;            // [128][64] dry (32 KB)
    float* ktile = dtile + 128 * 64;     // [128][64] K   (32 KB)
    {
        int n2 = t >> 3;                 // 0..127
        int cc = (t & 7) << 3;           // 0..56
        const float* eb = events + (size_t)a * NEV * N_T;
        const int* ib = indices + a * NEV;
        const float* wb = wroom + a * NROOM;
        float4 dA = make_float4(0.f, 0.f, 0.f, 0.f), dB = dA;
#pragma unroll
        for (int e = 0; e < NEV; e++) {
            int s = ib[e];
            if (n2 >= s) {
                const float* er = eb + e * N_T + ((n2 - s) << 8) + c0 + cc;
                float4 vA = *(const float4*)er;
                float4 vB = *(const float4*)(er + 4);
                dA.x += vA.x; dA.y += vA.y; dA.z += vA.z; dA.w += vA.w;
                dB.x += vB.x; dB.y += vB.y; dB.z += vB.z; dB.w += vB.w;
            }
        }
        float4 kA = make_float4(0.f, 0.f, 0.f, 0.f), kB = kA;
#pragma unroll
        for (int r = 0; r < NROOM; r++) {
            float w = wb[r];
            const float* rr = rooms + (size_t)r * N_T + (n2 << 8) + c0 + cc;
            float4 vA = *(const float4*)rr;
            float4 vB = *(const float4*)(rr + 4);
            kA.x += w * vA.x; kA.y += w * vA.y; kA.z += w * vA.z; kA.w += w * vA.w;
            kB.x += w * vB.x; kB.y += w * vB.y; kB.z += w * vB.z; kB.w += w * vB.w;
        }
        float* db = dryf + (size_t)a * N_T + (n2 << 8) + c0 + cc;
        *(float4*)db = dA;
        *(float4*)(db + 4) = dB;
        *(float4*)&dtile[(n2 << 6) + cc] = dA;
        *(float4*)&dtile[(n2 << 6) + cc + 4] = dB;
        *(float4*)&ktile[(n2 << 6) + cc] = kA;
        *(float4*)&ktile[(n2 << 6) + cc + 4] = kB;
    }
    __syncthreads();
    int j = t >> 6, c = t & 63;
    int n1 = c0 + c;
    float2 r[16];
#pragma unroll
    for (int m = 0; m < 8; m++) {
        int n2 = j + 16 * m;             // < 128 always
        r[m] = make_float2(dtile[(n2 << 6) + c], ktile[(n2 << 6) + c]);
    }
#pragma unroll
    for (int m = 8; m < 16; m++) r[m] = make_float2(0.f, 0.f);
    // stages 1-2 in registers
#pragma unroll
    for (int m0 = 0; m0 < 4; m0++) bf4f(r[m0], r[m0 + 4], r[m0 + 8], r[m0 + 12], tw, 1, j + 16 * m0);
#pragma unroll
    for (int h = 0; h < 4; h++) bf4f(r[4 * h], r[4 * h + 1], r[4 * h + 2], r[4 * h + 3], tw, 4, j);
    __syncthreads();                     // staging reads done; T reusable
    // two-round transpose through 128-row buffer
    float2 r2[16];
#pragma unroll
    for (int m = 0; m < 8; m++) T[(j + 16 * m) * TWP + c] = r[m];
    __syncthreads();
    if (j < 8) {
#pragma unroll
        for (int jj = 0; jj < 16; jj++) r2[jj] = T[(jj + 16 * j) * TWP + c];
    }
    __syncthreads();
#pragma unroll
    for (int m = 8; m < 16; m++) T[(j + 16 * m - 128) * TWP + c] = r[m];
    __syncthreads();
    if (j >= 8) {
#pragma unroll
        for (int jj = 0; jj < 16; jj++) r2[jj] = T[(jj + 16 * (j - 8)) * TWP + c];
    }
    // stages 3-4
#pragma unroll
    for (int q = 0; q < 4; q++) bf4f(r2[q], r2[q + 4], r2[q + 8], r2[q + 12], tw, 16, q);
#pragma unroll
    for (int h = 0; h < 4; h++) bf4f(r2[4 * h], r2[4 * h + 1], r2[4 * h + 2], r2[4 * h + 3], tw, 64, 0);
#pragma unroll
    for (int jj = 0; jj < 16; jj++) {
        int p = jj + 16 * j;
        int k2 = dr4(p);
        int ph = (n1 * k2) & (L - 1);
        float2 w = cmul(tw[ph >> 8], fine[ph & 255]);
        base[n1 + (p << 8)] = cmul(r2[jj], w);   // 64 lanes x 8B = 512B contiguous
    }
}

// ---- pointwise unit (LDS form) ----
__device__ __forceinline__ void pw_unit(float2* A, int sJ, int kJ, int sN, int kN) {
    float2 Z0j = A[sJ * ROWP + kJ],       Z0n = A[sN * ROWP + kN];
    float2 Z1j = A[(4 + sJ) * ROWP + kJ], Z1n = A[(4 + sN) * ROWP + kN];
    float2 D0 = make_float2(0.5f * (Z0j.x + Z0n.x), 0.5f * (Z0j.y - Z0n.y));
    float2 K0 = make_float2(0.5f * (Z0j.y + Z0n.y), 0.5f * (Z0n.x - Z0j.x));
    float2 D1 = make_float2(0.5f * (Z1j.x + Z1n.x), 0.5f * (Z1j.y - Z1n.y));
    float2 K1 = make_float2(0.5f * (Z1j.y + Z1n.y), 0.5f * (Z1n.x - Z1j.x));
    float2 W0 = cmul(D0, K0);
    float2 W1 = cmul(D1, K1);
    A[sJ * ROWP + kJ] = make_float2(W0.x - W1.y, W0.y + W1.x);
    A[sN * ROWP + kN] = make_float2(W0.x + W1.y, W1.x - W0.y);
}

// ---- fused row pass (R6-verbatim): fwd radix-4 DIF (8 rows) -> pw -> inv DIT (4 rows) ----
__global__ void k_rowpw(float2* __restrict__ C) {
    __shared__ float2 A[8 * ROWP];
    __shared__ float2 tw[192];
    int t = threadIdx.x;
    int p = blockIdx.x >> 6;
    int g = blockIdx.x & 63;
    int rows[4];
    if (g == 0) { rows[0] = 0; rows[1] = 1; rows[2] = 128; rows[3] = 255; }
    else        { rows[0] = 2 * g; rows[1] = 2 * g + 1; rows[2] = 256 - 2 * g; rows[3] = 255 - 2 * g; }
    if (t < 192) {
        float sv, cv;
        __sincosf(-TWO_PI * (float)t * (1.0f / 256.0f), &sv, &cv);
        tw[t] = make_float2(cv, sv);
    }
    float2* b0 = C + (size_t)(2 * p) * L;
    float2* b1 = b0 + L;
    for (int u = t; u < 1024; u += 256) {
        int slot = u >> 7;
        int f = (u & 127) << 1;
        const float2* arr = (slot < 4) ? b0 : b1;
        int grow = dr4(rows[slot & 3]);
        float4 v = *(const float4*)(arr + (grow << 8) + f);
        *(float4*)&A[slot * ROWP + f] = v;
    }
    __syncthreads();
#pragma unroll
    for (int lm = 8; lm >= 6; lm -= 2) {
        int Q = 1 << (lm - 2), f = 256 >> lm;
        for (int u = t; u < 512; u += 256) {
            int row = u >> 6, qi = u & 63;
            int q = qi & (Q - 1);
            int i0 = ((qi - q) << 2) + q;
            bfly4_fwd(A, row * ROWP + i0, Q, tw, f, q);
        }
        __syncthreads();
    }
#pragma unroll
    for (int lm = 4; lm >= 2; lm -= 2) {
        int Q = 1 << (lm - 2), f = 256 >> lm;
        for (int u = t; u < 512; u += 256) {
            int row = u & 7, qi = u >> 3;
            int q = qi & (Q - 1);
            int i0 = ((qi - q) << 2) + q;
            bfly4_fwd(A, row * ROWP + i0, Q, tw, f, q);
        }
        __syncthreads();
    }
    if (g) {
        pw_unit(A, 0, t, 2, 255 - t);
    } else {
        if (t == 0)      { pw_unit(A, 0, 0, 0, 0); pw_unit(A, 0, 2, 0, 2); }
        else if (t < 128) pw_unit(A, 0, dr4(t), 0, dr4(256 - t));
        else              { int qq = t - 128; pw_unit(A, 2, qq, 2, 255 - qq); }
    }
    pw_unit(A, 1, t, 3, 255 - t);
    __syncthreads();
#pragma unroll
    for (int lm = 2; lm <= 4; lm += 2) {
        int Q = 1 << (lm - 2), f = 256 >> lm;
        int row = t & 3, qi = t >> 2;
        int q = qi & (Q - 1);
        int i0 = ((qi - q) << 2) + q;
        bfly4_inv(A, row * ROWP + i0, Q, tw, f, q);
        __syncthreads();
    }
#pragma unroll
    for (int lm = 6; lm <= 8; lm += 2) {
        int Q = 1 << (lm - 2), f = 256 >> lm;
        int row = t >> 6, qi = t & 63;
        int q = qi & (Q - 1);
        int i0 = ((qi - q) << 2) + q;
        bfly4_inv(A, row * ROWP + i0, Q, tw, f, q);
        __syncthreads();
    }
    for (int u = t; u < 512; u += 256) {
        int slot = u >> 7;
        int f = (u & 127) << 1;
        int r = rows[slot];
        float2 va = A[slot * ROWP + f];
        float2 vb = A[slot * ROWP + f + 1];
        int pha = (f * r) & (L - 1);
        int phb = ((f + 1) * r) & (L - 1);
        float sa, ca, sb, cb2;
        __sincosf(TWO_PI * (float)pha * INV_L, &sa, &ca);
        __sincosf(TWO_PI * (float)phb * INV_L, &sb, &cb2);
        float2 ra = cmul(va, make_float2(ca, sa));
        float2 rb = cmul(vb, make_float2(cb2, sb));
        *(float4*)(b0 + (dr4(r) << 8) + f) = make_float4(ra.x, ra.y, rb.x, rb.y);
    }
}

// ---- wide inverse col pass: 512 threads, 32 columns; fused mix + partial max ----
__global__ __launch_bounds__(512) void k_colinv(const float2* __restrict__ C,
                                                const float* __restrict__ dryf,
                                                const float* __restrict__ mixv,
                                                float* __restrict__ out,
                                                float* __restrict__ partial) {
    __shared__ float2 T[128 * TWP2];
    __shared__ float2 tw[256];
    __shared__ float sm0[8], sm1[8];
    int t = threadIdx.x;
    int a = blockIdx.x >> 3;       // pair
    int cg = blockIdx.x & 7;       // 8 x 32 columns
    int c0 = cg * 32;
    const float2* base = C + (size_t)(2 * a) * L;
    if (t < 256) {
        float sv, cv;
        __sincosf(-TWO_PI * (float)t * (1.0f / 256.0f), &sv, &cv);
        tw[t] = make_float2(cv, sv);
    }
    int j = t >> 5, c = t & 31;
    int n1 = c0 + c;
    float2 r[16];
#pragma unroll
    for (int jj = 0; jj < 16; jj++) r[jj] = base[n1 + ((jj + 16 * j) << 8)];
    __syncthreads();
#pragma unroll
    for (int h = 0; h < 4; h++) bf4i(r[4 * h], r[4 * h + 1], r[4 * h + 2], r[4 * h + 3], tw, 64, 0);
#pragma unroll
    for (int q = 0; q < 4; q++) bf4i(r[q], r[q + 4], r[q + 8], r[q + 12], tw, 16, q);
    // two-round transpose
    float2 r2[16];
    if (j < 8) {
#pragma unroll
        for (int jj = 0; jj < 16; jj++) T[(jj + 16 * j) * TWP2 + c] = r[jj];
    }
    __syncthreads();
#pragma unroll
    for (int m = 0; m < 8; m++) r2[m] = T[(j + 16 * m) * TWP2 + c];
    __syncthreads();
    if (j >= 8) {
#pragma unroll
        for (int jj = 0; jj < 16; jj++) T[(16 * (j - 8) + jj) * TWP2 + c] = r[jj];
    }
    __syncthreads();
#pragma unroll
    for (int m = 8; m < 16; m++) r2[m] = T[(j + 16 * (m - 8)) * TWP2 + c];
#pragma unroll
    for (int h = 0; h < 4; h++) bf4i(r2[4 * h], r2[4 * h + 1], r2[4 * h + 2], r2[4 * h + 3], tw, 4, j);
#pragma unroll
    for (int m0 = 0; m0 < 4; m0++) bf4i(r2[m0], r2[m0 + 4], r2[m0 + 8], r2[m0 + 12], tw, 1, j + 16 * m0);
    int b0 = 2 * a, b1 = 2 * a + 1;
    float mix0 = mixv[b0], mix1 = mixv[b1];
    float om0 = 1.f - mix0, om1 = 1.f - mix1;
    const float* dry0 = dryf + (size_t)b0 * N_T;
    const float* dry1 = dryf + (size_t)b1 * N_T;
    float* out0 = out + (size_t)b0 * N_T;
    float* out1 = out + (size_t)b1 * N_T;
    float m0 = -3.4e38f, m1 = -3.4e38f;
#pragma unroll
    for (int m = 0; m < 8; m++) {
        int pos = n1 + ((j + 16 * m) << 8);      // n2 = j+16m < 128
        float d0 = dry0[pos], d1 = dry1[pos];
        float o0 = mix0 * (r2[m].x * INV_L) + om0 * d0;
        float o1 = mix1 * (r2[m].y * INV_L) + om1 * d1;
        out0[pos] = o0;
        out1[pos] = o1;
        m0 = fmaxf(m0, o0);
        m1 = fmaxf(m1, o1);
    }
#pragma unroll
    for (int off = 32; off > 0; off >>= 1) {
        m0 = fmaxf(m0, __shfl_down(m0, off));
        m1 = fmaxf(m1, __shfl_down(m1, off));
    }
    if ((t & 63) == 0) { sm0[t >> 6] = m0; sm1[t >> 6] = m1; }
    __syncthreads();
    if (t == 0) {
        float p0 = sm0[0], p1 = sm1[0];
#pragma unroll
        for (int w = 1; w < 8; w++) { p0 = fmaxf(p0, sm0[w]); p1 = fmaxf(p1, sm1[w]); }
        partial[b0 * 8 + cg] = p0;
        partial[b1 * 8 + cg] = p1;
    }
}

__global__ void k_norm(float* __restrict__ out, const float* __restrict__ partial) {
    int blk = blockIdx.x;
    int b = blk >> 5;
    int ch = blk & 31;
    __shared__ float smx;
    if (threadIdx.x < 8) {
        float p = partial[b * 8 + threadIdx.x];
#pragma unroll
        for (int off = 4; off > 0; off >>= 1) p = fmaxf(p, __shfl_down(p, off, 8));
        if (threadIdx.x == 0) smx = p;
    }
    __syncthreads();
    float inv = 1.f / (smx + 1e-8f);
    size_t base = (size_t)b * N_T + ch * 1024 + threadIdx.x * 4;
    float4 o = *(const float4*)(out + base);
    o.x *= inv; o.y *= inv; o.z *= inv; o.w *= inv;
    *(float4*)(out + base) = o;
}

extern "C" void kernel_launch(void* const* d_in, const int* in_sizes, int n_in,
                              void* d_out, int out_size, void* d_ws, size_t ws_size,
                              hipStream_t stream) {
    const float* events = (const float*)d_in[0];
    const int* indices = (const int*)d_in[1];
    const float* g      = (const float*)d_in[2];
    const float* rooms  = (const float*)d_in[3];
    const float* w_room = (const float*)d_in[4];
    const float* b_room = (const float*)d_in[5];
    const float* w_mix  = (const float*)d_in[6];
    const float* b_mix  = (const float*)d_in[7];
    float* out = (float*)d_out;

    char* ws = (char*)d_ws;
    float2* C = (float2*)ws;  // [64][65536] complex: Z_b = dry_b + i*K_b (spectral)
    size_t off = (size_t)BATCH * L * sizeof(float2);
    float* dryf = (float*)(ws + off);
    off += (size_t)BATCH * N_T * sizeof(float);
    float* wroom = (float*)(ws + off);
    off += BATCH * NROOM * sizeof(float);
    float* mixv = (float*)(ws + off);
    off += BATCH * sizeof(float);
    float* partial = (float*)(ws + off);

    k_prep<<<1, 64, 0, stream>>>(g, w_room, b_room, w_mix, b_mix, wroom, mixv);
    k_fwd<<<BATCH * 4, 1024, 0, stream>>>(events, indices, rooms, wroom, dryf, C);
    k_rowpw<<<NPAIR * 64, 256, 0, stream>>>(C);
    k_colinv<<<NPAIR * 8, 512, 0, stream>>>(C, dryf, mixv, out, partial);
    k_norm<<<BATCH * 32, 256, 0, stream>>>(out, partial);
}

// Round 15
// 75.666 us; speedup vs baseline: 1.4842x; 1.0041x over previous
//
#include <hip/hip_runtime.h>
#include <math.h>

#define N_T 32768
#define L 65536
#define BATCH 64
#define NPAIR 32
#define NEV 8
#define NROOM 16
#define ROWP 258
#define TWP 65                 // k_fwd transpose pad (64 cols)
#define TWP2 33                // colinv transpose pad (32 cols)
#define TILE 16384             // float2 per C tile: [256 p][64 c]
#define TWO_PI 6.2831853071795864769f
#define INV_L (1.0f / 65536.0f)

__device__ __forceinline__ float2 cmul(float2 a, float2 b) {
    return make_float2(a.x * b.x - a.y * b.y, a.x * b.y + a.y * b.x);
}
// base-4 digit reversal of an 8-bit index (involution)
__device__ __forceinline__ int dr4(int p) {
    return ((p & 3) << 6) | ((p & 12) << 2) | ((p & 48) >> 2) | ((p & 192) >> 6);
}

// register radix-4 DIF butterfly (fwd)
__device__ __forceinline__ void bf4f(float2& a, float2& b, float2& c, float2& d,
                                     const float2* tw, int f, int q) {
    float2 t0 = make_float2(a.x + c.x, a.y + c.y);
    float2 t1 = make_float2(a.x - c.x, a.y - c.y);
    float2 t2 = make_float2(b.x + d.x, b.y + d.y);
    float2 u  = make_float2(b.x - d.x, b.y - d.y);
    float2 t3 = make_float2(u.y, -u.x);            // -i*u
    a = make_float2(t0.x + t2.x, t0.y + t2.y);
    b = cmul(make_float2(t1.x + t3.x, t1.y + t3.y), tw[f * q]);
    c = cmul(make_float2(t0.x - t2.x, t0.y - t2.y), tw[2 * f * q]);
    d = cmul(make_float2(t1.x - t3.x, t1.y - t3.y), tw[3 * f * q]);
}
// register radix-4 DIT butterfly (inv): exact inverse of bf4f
__device__ __forceinline__ void bf4i(float2& a, float2& b, float2& c, float2& d,
                                     const float2* tw, int f, int q) {
    float2 w1 = tw[f * q], w2 = tw[2 * f * q], w3 = tw[3 * f * q];
    float2 y0 = a;
    float2 y1 = cmul(b, make_float2(w1.x, -w1.y));
    float2 y2 = cmul(c, make_float2(w2.x, -w2.y));
    float2 y3 = cmul(d, make_float2(w3.x, -w3.y));
    float2 t0 = make_float2(y0.x + y2.x, y0.y + y2.y);
    float2 t2 = make_float2(y0.x - y2.x, y0.y - y2.y);
    float2 t1 = make_float2(y1.x + y3.x, y1.y + y3.y);
    float2 u  = make_float2(y1.x - y3.x, y1.y - y3.y);
    a = make_float2(t0.x + t1.x, t0.y + t1.y);
    b = make_float2(t2.x - u.y, t2.y + u.x);
    c = make_float2(t0.x - t1.x, t0.y - t1.y);
    d = make_float2(t2.x + u.y, t2.y - u.x);
}
__device__ __forceinline__ void bfly4_fwd(float2* A, int a0, int st, const float2* tw, int f, int q) {
    bf4f(A[a0], A[a0 + st], A[a0 + 2 * st], A[a0 + 3 * st], tw, f, q);
}
__device__ __forceinline__ void bfly4_inv(float2* A, int a0, int st, const float2* tw, int f, int q) {
    bf4i(A[a0], A[a0 + st], A[a0 + 2 * st], A[a0 + 3 * st], tw, f, q);
}

// ---- gating ----
__global__ void k_prep(const float* __restrict__ g, const float* __restrict__ w_room,
                       const float* __restrict__ b_room, const float* __restrict__ w_mix,
                       const float* __restrict__ b_mix,
                       float* __restrict__ wroom, float* __restrict__ mixv) {
    int b = threadIdx.x;
    if (b >= BATCH) return;
    float logits[NROOM];
    for (int r = 0; r < NROOM; r++) logits[r] = b_room[r];
    float acc_mix = b_mix[0];
    for (int d = 0; d < 128; d++) {
        float gv = g[b * 128 + d];
        for (int r = 0; r < NROOM; r++) logits[r] += gv * w_room[d * NROOM + r];
        acc_mix += gv * w_mix[d];
    }
    float m = logits[0];
    for (int r = 1; r < NROOM; r++) m = fmaxf(m, logits[r]);
    float s = 0.f;
    for (int r = 0; r < NROOM; r++) { logits[r] = expf(logits[r] - m); s += logits[r]; }
    float inv = 1.f / s;
    for (int r = 0; r < NROOM; r++) wroom[b * NROOM + r] = logits[r] * inv;
    mixv[b] = 1.f / (1.f + expf(-acc_mix));
}

// ---- fused wide col pass: stage dry+K (64 cols), write dryf, radix-4 fwd FFT, big twiddle ----
// Output into tile (a, cg): [256 p][64 c] float2, written fully streaming.
__global__ __launch_bounds__(1024) void k_fwd(const float* __restrict__ events,
                                              const int* __restrict__ indices,
                                              const float* __restrict__ rooms,
                                              const float* __restrict__ wroom,
                                              float* __restrict__ dryf, float2* __restrict__ C) {
    __shared__ float2 T[128 * TWP];      // 66.5 KB; front 64 KB doubles as dry/K staging
    __shared__ float2 tw[256];
    __shared__ float2 fine[256];
    int t = threadIdx.x;
    int a = blockIdx.x >> 2;             // batch
    int cg = blockIdx.x & 3;             // column group (4 x 64)
    int c0 = cg * 64;
    float2* tile = C + ((size_t)(a * 4 + cg)) * TILE;
    if (t < 256) {
        float sv, cv;
        __sincosf(-TWO_PI * (float)t * (1.0f / 256.0f), &sv, &cv);
        tw[t] = make_float2(cv, sv);
        __sincosf(-TWO_PI * (float)t * INV_L, &sv, &cv);
        fine[t] = make_float2(cv, sv);
    }
    float* dtile = (float*)T;            // [128][64] dry (32 KB)
    float* ktile = dtile + 128 * 64;     // [128][64] K   (32 KB)
    {
        int n2 = t >> 3;                 // 0..127
        int cc = (t & 7) << 3;           // 0..56
        const float* eb = events + (size_t)a * NEV * N_T;
        const int* ib = indices + a * NEV;
        const float* wb = wroom + a * NROOM;
        float4 dA = make_float4(0.f, 0.f, 0.f, 0.f), dB = dA;
#pragma unroll
        for (int e = 0; e < NEV; e++) {
            int s = ib[e];
            if (n2 >= s) {
                const float* er = eb + e * N_T + ((n2 - s) << 8) + c0 + cc;
                float4 vA = *(const float4*)er;
                float4 vB = *(const float4*)(er + 4);
                dA.x += vA.x; dA.y += vA.y; dA.z += vA.z; dA.w += vA.w;
                dB.x += vB.x; dB.y += vB.y; dB.z += vB.z; dB.w += vB.w;
            }
        }
        float4 kA = make_float4(0.f, 0.f, 0.f, 0.f), kB = kA;
#pragma unroll
        for (int r = 0; r < NROOM; r++) {
            float w = wb[r];
            const float* rr = rooms + (size_t)r * N_T + (n2 << 8) + c0 + cc;
            float4 vA = *(const float4*)rr;
            float4 vB = *(const float4*)(rr + 4);
            kA.x += w * vA.x; kA.y += w * vA.y; kA.z += w * vA.z; kA.w += w * vA.w;
            kB.x += w * vB.x; kB.y += w * vB.y; kB.z += w * vB.z; kB.w += w * vB.w;
        }
        float* db = dryf + (size_t)a * N_T + (n2 << 8) + c0 + cc;
        *(float4*)db = dA;
        *(float4*)(db + 4) = dB;
        *(float4*)&dtile[(n2 << 6) + cc] = dA;
        *(float4*)&dtile[(n2 << 6) + cc + 4] = dB;
        *(float4*)&ktile[(n2 << 6) + cc] = kA;
        *(float4*)&ktile[(n2 << 6) + cc + 4] = kB;
    }
    __syncthreads();
    int j = t >> 6, c = t & 63;
    int n1 = c0 + c;
    float2 r[16];
#pragma unroll
    for (int m = 0; m < 8; m++) {
        int n2 = j + 16 * m;             // < 128 always
        r[m] = make_float2(dtile[(n2 << 6) + c], ktile[(n2 << 6) + c]);
    }
#pragma unroll
    for (int m = 8; m < 16; m++) r[m] = make_float2(0.f, 0.f);
    // stages 1-2 in registers
#pragma unroll
    for (int m0 = 0; m0 < 4; m0++) bf4f(r[m0], r[m0 + 4], r[m0 + 8], r[m0 + 12], tw, 1, j + 16 * m0);
#pragma unroll
    for (int h = 0; h < 4; h++) bf4f(r[4 * h], r[4 * h + 1], r[4 * h + 2], r[4 * h + 3], tw, 4, j);
    __syncthreads();                     // staging reads done; T reusable
    // two-round transpose through 128-row buffer
    float2 r2[16];
#pragma unroll
    for (int m = 0; m < 8; m++) T[(j + 16 * m) * TWP + c] = r[m];
    __syncthreads();
    if (j < 8) {
#pragma unroll
        for (int jj = 0; jj < 16; jj++) r2[jj] = T[(jj + 16 * j) * TWP + c];
    }
    __syncthreads();
#pragma unroll
    for (int m = 8; m < 16; m++) T[(j + 16 * m - 128) * TWP + c] = r[m];
    __syncthreads();
    if (j >= 8) {
#pragma unroll
        for (int jj = 0; jj < 16; jj++) r2[jj] = T[(jj + 16 * (j - 8)) * TWP + c];
    }
    // stages 3-4
#pragma unroll
    for (int q = 0; q < 4; q++) bf4f(r2[q], r2[q + 4], r2[q + 8], r2[q + 12], tw, 16, q);
#pragma unroll
    for (int h = 0; h < 4; h++) bf4f(r2[4 * h], r2[4 * h + 1], r2[4 * h + 2], r2[4 * h + 3], tw, 64, 0);
#pragma unroll
    for (int jj = 0; jj < 16; jj++) {
        int p = jj + 16 * j;
        int k2 = dr4(p);
        int ph = (n1 * k2) & (L - 1);
        float2 w = cmul(tw[ph >> 8], fine[ph & 255]);
        tile[(p << 6) + c] = cmul(r2[jj], w);    // streaming 512B per wave op
    }
}

// ---- pointwise unit (LDS form) ----
__device__ __forceinline__ void pw_unit(float2* A, int sJ, int kJ, int sN, int kN) {
    float2 Z0j = A[sJ * ROWP + kJ],       Z0n = A[sN * ROWP + kN];
    float2 Z1j = A[(4 + sJ) * ROWP + kJ], Z1n = A[(4 + sN) * ROWP + kN];
    float2 D0 = make_float2(0.5f * (Z0j.x + Z0n.x), 0.5f * (Z0j.y - Z0n.y));
    float2 K0 = make_float2(0.5f * (Z0j.y + Z0n.y), 0.5f * (Z0n.x - Z0j.x));
    float2 D1 = make_float2(0.5f * (Z1j.x + Z1n.x), 0.5f * (Z1j.y - Z1n.y));
    float2 K1 = make_float2(0.5f * (Z1j.y + Z1n.y), 0.5f * (Z1n.x - Z1j.x));
    float2 W0 = cmul(D0, K0);
    float2 W1 = cmul(D1, K1);
    A[sJ * ROWP + kJ] = make_float2(W0.x - W1.y, W0.y + W1.x);
    A[sN * ROWP + kN] = make_float2(W0.x + W1.y, W1.x - W0.y);
}

// ---- fused row pass: fwd radix-4 DIF (8 rows) -> pointwise -> inv DIT (4 rows) ----
// Rows are gathered from the 4 tiles per array (512B per tile-row chunk).
__global__ void k_rowpw(float2* __restrict__ C) {
    __shared__ float2 A[8 * ROWP];
    __shared__ float2 tw[192];
    int t = threadIdx.x;
    int p = blockIdx.x >> 6;
    int g = blockIdx.x & 63;
    int rows[4];
    if (g == 0) { rows[0] = 0; rows[1] = 1; rows[2] = 128; rows[3] = 255; }
    else        { rows[0] = 2 * g; rows[1] = 2 * g + 1; rows[2] = 256 - 2 * g; rows[3] = 255 - 2 * g; }
    if (t < 192) {
        float sv, cv;
        __sincosf(-TWO_PI * (float)t * (1.0f / 256.0f), &sv, &cv);
        tw[t] = make_float2(cv, sv);
    }
    float2* b0 = C + ((size_t)(2 * p) * 4) * TILE;
    float2* b1 = b0 + 4 * TILE;
    for (int u = t; u < 1024; u += 256) {
        int slot = u >> 7;
        int f = (u & 127) << 1;          // n1, even
        int cg = f >> 6, c2 = f & 63;
        const float2* arr = (slot < 4) ? b0 : b1;
        int grow = dr4(rows[slot & 3]);
        float4 v = *(const float4*)(arr + cg * TILE + (grow << 6) + c2);
        *(float4*)&A[slot * ROWP + f] = v;
    }
    __syncthreads();
#pragma unroll
    for (int lm = 8; lm >= 6; lm -= 2) {
        int Q = 1 << (lm - 2), f = 256 >> lm;
        for (int u = t; u < 512; u += 256) {
            int row = u >> 6, qi = u & 63;
            int q = qi & (Q - 1);
            int i0 = ((qi - q) << 2) + q;
            bfly4_fwd(A, row * ROWP + i0, Q, tw, f, q);
        }
        __syncthreads();
    }
#pragma unroll
    for (int lm = 4; lm >= 2; lm -= 2) {
        int Q = 1 << (lm - 2), f = 256 >> lm;
        for (int u = t; u < 512; u += 256) {
            int row = u & 7, qi = u >> 3;
            int q = qi & (Q - 1);
            int i0 = ((qi - q) << 2) + q;
            bfly4_fwd(A, row * ROWP + i0, Q, tw, f, q);
        }
        __syncthreads();
    }
    if (g) {
        pw_unit(A, 0, t, 2, 255 - t);
    } else {
        if (t == 0)      { pw_unit(A, 0, 0, 0, 0); pw_unit(A, 0, 2, 0, 2); }
        else if (t < 128) pw_unit(A, 0, dr4(t), 0, dr4(256 - t));
        else              { int qq = t - 128; pw_unit(A, 2, qq, 2, 255 - qq); }
    }
    pw_unit(A, 1, t, 3, 255 - t);
    __syncthreads();
#pragma unroll
    for (int lm = 2; lm <= 4; lm += 2) {
        int Q = 1 << (lm - 2), f = 256 >> lm;
        int row = t & 3, qi = t >> 2;
        int q = qi & (Q - 1);
        int i0 = ((qi - q) << 2) + q;
        bfly4_inv(A, row * ROWP + i0, Q, tw, f, q);
        __syncthreads();
    }
#pragma unroll
    for (int lm = 6; lm <= 8; lm += 2) {
        int Q = 1 << (lm - 2), f = 256 >> lm;
        int row = t >> 6, qi = t & 63;
        int q = qi & (Q - 1);
        int i0 = ((qi - q) << 2) + q;
        bfly4_inv(A, row * ROWP + i0, Q, tw, f, q);
        __syncthreads();
    }
    for (int u = t; u < 512; u += 256) {
        int slot = u >> 7;
        int f = (u & 127) << 1;
        int cg = f >> 6, c2 = f & 63;
        int r = rows[slot];
        float2 va = A[slot * ROWP + f];
        float2 vb = A[slot * ROWP + f + 1];
        int pha = (f * r) & (L - 1);
        int phb = ((f + 1) * r) & (L - 1);
        float sa, ca, sb, cb2;
        __sincosf(TWO_PI * (float)pha * INV_L, &sa, &ca);
        __sincosf(TWO_PI * (float)phb * INV_L, &sb, &cb2);
        float2 ra = cmul(va, make_float2(ca, sa));
        float2 rb = cmul(vb, make_float2(cb2, sb));
        *(float4*)(b0 + cg * TILE + (dr4(r) << 6) + c2) = make_float4(ra.x, ra.y, rb.x, rb.y);
    }
}

// ---- inverse col pass: 512 threads, 32 columns; tile reads at 512B stride; mix+max ----
__global__ __launch_bounds__(512) void k_colinv(const float2* __restrict__ C,
                                                const float* __restrict__ dryf,
                                                const float* __restrict__ mixv,
                                                float* __restrict__ out,
                                                float* __restrict__ partial) {
    __shared__ float2 T[128 * TWP2];
    __shared__ float2 tw[256];
    __shared__ float sm0[8], sm1[8];
    int t = threadIdx.x;
    int a = blockIdx.x >> 3;       // pair
    int cgrp = blockIdx.x & 7;     // 8 x 32 columns
    int c0 = cgrp * 32;
    const float2* tile = C + ((size_t)(2 * a * 4 + (c0 >> 6))) * TILE;
    int coff = c0 & 63;
    if (t < 256) {
        float sv, cv;
        __sincosf(-TWO_PI * (float)t * (1.0f / 256.0f), &sv, &cv);
        tw[t] = make_float2(cv, sv);
    }
    int j = t >> 5, c = t & 31;
    int n1 = c0 + c;
    float2 r[16];
#pragma unroll
    for (int jj = 0; jj < 16; jj++) r[jj] = tile[((jj + 16 * j) << 6) + coff + c];
    __syncthreads();
#pragma unroll
    for (int h = 0; h < 4; h++) bf4i(r[4 * h], r[4 * h + 1], r[4 * h + 2], r[4 * h + 3], tw, 64, 0);
#pragma unroll
    for (int q = 0; q < 4; q++) bf4i(r[q], r[q + 4], r[q + 8], r[q + 12], tw, 16, q);
    // two-round transpose
    float2 r2[16];
    if (j < 8) {
#pragma unroll
        for (int jj = 0; jj < 16; jj++) T[(jj + 16 * j) * TWP2 + c] = r[jj];
    }
    __syncthreads();
#pragma unroll
    for (int m = 0; m < 8; m++) r2[m] = T[(j + 16 * m) * TWP2 + c];
    __syncthreads();
    if (j >= 8) {
#pragma unroll
        for (int jj = 0; jj < 16; jj++) T[(16 * (j - 8) + jj) * TWP2 + c] = r[jj];
    }
    __syncthreads();
#pragma unroll
    for (int m = 8; m < 16; m++) r2[m] = T[(j + 16 * (m - 8)) * TWP2 + c];
#pragma unroll
    for (int h = 0; h < 4; h++) bf4i(r2[4 * h], r2[4 * h + 1], r2[4 * h + 2], r2[4 * h + 3], tw, 4, j);
#pragma unroll
    for (int m0 = 0; m0 < 4; m0++) bf4i(r2[m0], r2[m0 + 4], r2[m0 + 8], r2[m0 + 12], tw, 1, j + 16 * m0);
    int b0 = 2 * a, b1 = 2 * a + 1;
    float mix0 = mixv[b0], mix1 = mixv[b1];
    float om0 = 1.f - mix0, om1 = 1.f - mix1;
    const float* dry0 = dryf + (size_t)b0 * N_T;
    const float* dry1 = dryf + (size_t)b1 * N_T;
    float* out0 = out + (size_t)b0 * N_T;
    float* out1 = out + (size_t)b1 * N_T;
    float m0 = -3.4e38f, m1 = -3.4e38f;
#pragma unroll
    for (int m = 0; m < 8; m++) {
        int pos = n1 + ((j + 16 * m) << 8);      // n2 = j+16m < 128
        float d0 = dry0[pos], d1 = dry1[pos];
        float o0 = mix0 * (r2[m].x * INV_L) + om0 * d0;
        float o1 = mix1 * (r2[m].y * INV_L) + om1 * d1;
        out0[pos] = o0;
        out1[pos] = o1;
        m0 = fmaxf(m0, o0);
        m1 = fmaxf(m1, o1);
    }
#pragma unroll
    for (int off = 32; off > 0; off >>= 1) {
        m0 = fmaxf(m0, __shfl_down(m0, off));
        m1 = fmaxf(m1, __shfl_down(m1, off));
    }
    if ((t & 63) == 0) { sm0[t >> 6] = m0; sm1[t >> 6] = m1; }
    __syncthreads();
    if (t == 0) {
        float p0 = sm0[0], p1 = sm1[0];
#pragma unroll
        for (int w = 1; w < 8; w++) { p0 = fmaxf(p0, sm0[w]); p1 = fmaxf(p1, sm1[w]); }
        partial[b0 * 8 + cgrp] = p0;
        partial[b1 * 8 + cgrp] = p1;
    }
}

__global__ void k_norm(float* __restrict__ out, const float* __restrict__ partial) {
    int blk = blockIdx.x;
    int b = blk >> 5;
    int ch = blk & 31;
    __shared__ float smx;
    if (threadIdx.x < 8) {
        float p = partial[b * 8 + threadIdx.x];
#pragma unroll
        for (int off = 4; off > 0; off >>= 1) p = fmaxf(p, __shfl_down(p, off, 8));
        if (threadIdx.x == 0) smx = p;
    }
    __syncthreads();
    float inv = 1.f / (smx + 1e-8f);
    size_t base = (size_t)b * N_T + ch * 1024 + threadIdx.x * 4;
    float4 o = *(const float4*)(out + base);
    o.x *= inv; o.y *= inv; o.z *= inv; o.w *= inv;
    *(float4*)(out + base) = o;
}

extern "C" void kernel_launch(void* const* d_in, const int* in_sizes, int n_in,
                              void* d_out, int out_size, void* d_ws, size_t ws_size,
                              hipStream_t stream) {
    const float* events = (const float*)d_in[0];
    const int* indices = (const int*)d_in[1];
    const float* g      = (const float*)d_in[2];
    const float* rooms  = (const float*)d_in[3];
    const float* w_room = (const float*)d_in[4];
    const float* b_room = (const float*)d_in[5];
    const float* w_mix  = (const float*)d_in[6];
    const float* b_mix  = (const float*)d_in[7];
    float* out = (float*)d_out;

    char* ws = (char*)d_ws;
    float2* C = (float2*)ws;  // [64 batches][4 tiles][256 p][64 c] float2
    size_t off = (size_t)BATCH * L * sizeof(float2);
    float* dryf = (float*)(ws + off);
    off += (size_t)BATCH * N_T * sizeof(float);
    float* wroom = (float*)(ws + off);
    off += BATCH * NROOM * sizeof(float);
    float* mixv = (float*)(ws + off);
    off += BATCH * sizeof(float);
    float* partial = (float*)(ws + off);

    k_prep<<<1, 64, 0, stream>>>(g, w_room, b_room, w_mix, b_mix, wroom, mixv);
    k_fwd<<<BATCH * 4, 1024, 0, stream>>>(events, indices, rooms, wroom, dryf, C);
    k_rowpw<<<NPAIR * 64, 256, 0, stream>>>(C);
    k_colinv<<<NPAIR * 8, 512, 0, stream>>>(C, dryf, mixv, out, partial);
    k_norm<<<BATCH * 32, 256, 0, stream>>>(out, partial);
}

// Round 16
// 70.947 us; speedup vs baseline: 1.5829x; 1.0665x over previous
//
#include <hip/hip_runtime.h>
#include <hip/hip_fp16.h>
#include <math.h>

#define N_T 32768
#define L 65536
#define BATCH 64
#define NPAIR 32
#define NEV 8
#define NROOM 16
#define ROWP 258
#define TWP 65                 // k_fwd transpose pad (64 cols)
#define TWP2 33                // colinv transpose pad (32 cols)
#define TILE 16384             // half2 elements per C tile: [256 p][64 c]
#define TWO_PI 6.2831853071795864769f
#define INV_L (1.0f / 65536.0f)
#define PW_SCALE (1.0f / 256.0f)   // half of 1/L folded at pointwise
#define COL_SCALE (1.0f / 256.0f)  // other half at colinv

__device__ __forceinline__ float2 cmul(float2 a, float2 b) {
    return make_float2(a.x * b.x - a.y * b.y, a.x * b.y + a.y * b.x);
}
// base-4 digit reversal of an 8-bit index (involution)
__device__ __forceinline__ int dr4(int p) {
    return ((p & 3) << 6) | ((p & 12) << 2) | ((p & 48) >> 2) | ((p & 192) >> 6);
}

// register radix-4 DIF butterfly (fwd)
__device__ __forceinline__ void bf4f(float2& a, float2& b, float2& c, float2& d,
                                     const float2* tw, int f, int q) {
    float2 t0 = make_float2(a.x + c.x, a.y + c.y);
    float2 t1 = make_float2(a.x - c.x, a.y - c.y);
    float2 t2 = make_float2(b.x + d.x, b.y + d.y);
    float2 u  = make_float2(b.x - d.x, b.y - d.y);
    float2 t3 = make_float2(u.y, -u.x);            // -i*u
    a = make_float2(t0.x + t2.x, t0.y + t2.y);
    b = cmul(make_float2(t1.x + t3.x, t1.y + t3.y), tw[f * q]);
    c = cmul(make_float2(t0.x - t2.x, t0.y - t2.y), tw[2 * f * q]);
    d = cmul(make_float2(t1.x - t3.x, t1.y - t3.y), tw[3 * f * q]);
}
// register radix-4 DIT butterfly (inv): exact inverse of bf4f
__device__ __forceinline__ void bf4i(float2& a, float2& b, float2& c, float2& d,
                                     const float2* tw, int f, int q) {
    float2 w1 = tw[f * q], w2 = tw[2 * f * q], w3 = tw[3 * f * q];
    float2 y0 = a;
    float2 y1 = cmul(b, make_float2(w1.x, -w1.y));
    float2 y2 = cmul(c, make_float2(w2.x, -w2.y));
    float2 y3 = cmul(d, make_float2(w3.x, -w3.y));
    float2 t0 = make_float2(y0.x + y2.x, y0.y + y2.y);
    float2 t2 = make_float2(y0.x - y2.x, y0.y - y2.y);
    float2 t1 = make_float2(y1.x + y3.x, y1.y + y3.y);
    float2 u  = make_float2(y1.x - y3.x, y1.y - y3.y);
    a = make_float2(t0.x + t1.x, t0.y + t1.y);
    b = make_float2(t2.x - u.y, t2.y + u.x);
    c = make_float2(t0.x - t1.x, t0.y - t1.y);
    d = make_float2(t2.x + u.y, t2.y - u.x);
}
__device__ __forceinline__ void bfly4_fwd(float2* A, int a0, int st, const float2* tw, int f, int q) {
    bf4f(A[a0], A[a0 + st], A[a0 + 2 * st], A[a0 + 3 * st], tw, f, q);
}
__device__ __forceinline__ void bfly4_inv(float2* A, int a0, int st, const float2* tw, int f, int q) {
    bf4i(A[a0], A[a0 + st], A[a0 + 2 * st], A[a0 + 3 * st], tw, f, q);
}

// ---- gating ----
__global__ void k_prep(const float* __restrict__ g, const float* __restrict__ w_room,
                       const float* __restrict__ b_room, const float* __restrict__ w_mix,
                       const float* __restrict__ b_mix,
                       float* __restrict__ wroom, float* __restrict__ mixv) {
    int b = threadIdx.x;
    if (b >= BATCH) return;
    float logits[NROOM];
    for (int r = 0; r < NROOM; r++) logits[r] = b_room[r];
    float acc_mix = b_mix[0];
    for (int d = 0; d < 128; d++) {
        float gv = g[b * 128 + d];
        for (int r = 0; r < NROOM; r++) logits[r] += gv * w_room[d * NROOM + r];
        acc_mix += gv * w_mix[d];
    }
    float m = logits[0];
    for (int r = 1; r < NROOM; r++) m = fmaxf(m, logits[r]);
    float s = 0.f;
    for (int r = 0; r < NROOM; r++) { logits[r] = expf(logits[r] - m); s += logits[r]; }
    float inv = 1.f / s;
    for (int r = 0; r < NROOM; r++) wroom[b * NROOM + r] = logits[r] * inv;
    mixv[b] = 1.f / (1.f + expf(-acc_mix));
}

// ---- fused wide col pass: stage dry+K (64 cols), write dryf (fp16), radix-4 fwd FFT,
// big twiddle, store C tile as half2 ----
__global__ __launch_bounds__(1024) void k_fwd(const float* __restrict__ events,
                                              const int* __restrict__ indices,
                                              const float* __restrict__ rooms,
                                              const float* __restrict__ wroom,
                                              __half* __restrict__ dryfh,
                                              __half2* __restrict__ C) {
    __shared__ float2 T[128 * TWP];      // 66.5 KB; front 64 KB doubles as dry/K staging
    __shared__ float2 tw[256];
    __shared__ float2 fine[256];
    int t = threadIdx.x;
    int a = blockIdx.x >> 2;             // batch
    int cg = blockIdx.x & 3;             // column group (4 x 64)
    int c0 = cg * 64;
    __half2* tile = C + ((size_t)(a * 4 + cg)) * TILE;
    if (t < 256) {
        float sv, cv;
        __sincosf(-TWO_PI * (float)t * (1.0f / 256.0f), &sv, &cv);
        tw[t] = make_float2(cv, sv);
        __sincosf(-TWO_PI * (float)t * INV_L, &sv, &cv);
        fine[t] = make_float2(cv, sv);
    }
    float* dtile = (float*)T;            // [128][64] dry (32 KB)
    float* ktile = dtile + 128 * 64;     // [128][64] K   (32 KB)
    {
        int n2 = t >> 3;                 // 0..127
        int cc = (t & 7) << 3;           // 0..56
        const float* eb = events + (size_t)a * NEV * N_T;
        const int* ib = indices + a * NEV;
        const float* wb = wroom + a * NROOM;
        float4 dA = make_float4(0.f, 0.f, 0.f, 0.f), dB = dA;
#pragma unroll
        for (int e = 0; e < NEV; e++) {
            int s = ib[e];
            if (n2 >= s) {
                const float* er = eb + e * N_T + ((n2 - s) << 8) + c0 + cc;
                float4 vA = *(const float4*)er;
                float4 vB = *(const float4*)(er + 4);
                dA.x += vA.x; dA.y += vA.y; dA.z += vA.z; dA.w += vA.w;
                dB.x += vB.x; dB.y += vB.y; dB.z += vB.z; dB.w += vB.w;
            }
        }
        float4 kA = make_float4(0.f, 0.f, 0.f, 0.f), kB = kA;
#pragma unroll
        for (int r = 0; r < NROOM; r++) {
            float w = wb[r];
            const float* rr = rooms + (size_t)r * N_T + (n2 << 8) + c0 + cc;
            float4 vA = *(const float4*)rr;
            float4 vB = *(const float4*)(rr + 4);
            kA.x += w * vA.x; kA.y += w * vA.y; kA.z += w * vA.z; kA.w += w * vA.w;
            kB.x += w * vB.x; kB.y += w * vB.y; kB.z += w * vB.z; kB.w += w * vB.w;
        }
        __half2 hd[4];
        hd[0] = __float22half2_rn(make_float2(dA.x, dA.y));
        hd[1] = __float22half2_rn(make_float2(dA.z, dA.w));
        hd[2] = __float22half2_rn(make_float2(dB.x, dB.y));
        hd[3] = __float22half2_rn(make_float2(dB.z, dB.w));
        *(float4*)(dryfh + (size_t)a * N_T + (n2 << 8) + c0 + cc) = *(float4*)hd;
        *(float4*)&dtile[(n2 << 6) + cc] = dA;
        *(float4*)&dtile[(n2 << 6) + cc + 4] = dB;
        *(float4*)&ktile[(n2 << 6) + cc] = kA;
        *(float4*)&ktile[(n2 << 6) + cc + 4] = kB;
    }
    __syncthreads();
    int j = t >> 6, c = t & 63;
    int n1 = c0 + c;
    float2 r[16];
#pragma unroll
    for (int m = 0; m < 8; m++) {
        int n2 = j + 16 * m;             // < 128 always
        r[m] = make_float2(dtile[(n2 << 6) + c], ktile[(n2 << 6) + c]);
    }
#pragma unroll
    for (int m = 8; m < 16; m++) r[m] = make_float2(0.f, 0.f);
    // stages 1-2 in registers
#pragma unroll
    for (int m0 = 0; m0 < 4; m0++) bf4f(r[m0], r[m0 + 4], r[m0 + 8], r[m0 + 12], tw, 1, j + 16 * m0);
#pragma unroll
    for (int h = 0; h < 4; h++) bf4f(r[4 * h], r[4 * h + 1], r[4 * h + 2], r[4 * h + 3], tw, 4, j);
    __syncthreads();                     // staging reads done; T reusable
    // two-round transpose through 128-row buffer
    float2 r2[16];
#pragma unroll
    for (int m = 0; m < 8; m++) T[(j + 16 * m) * TWP + c] = r[m];
    __syncthreads();
    if (j < 8) {
#pragma unroll
        for (int jj = 0; jj < 16; jj++) r2[jj] = T[(jj + 16 * j) * TWP + c];
    }
    __syncthreads();
#pragma unroll
    for (int m = 8; m < 16; m++) T[(j + 16 * m - 128) * TWP + c] = r[m];
    __syncthreads();
    if (j >= 8) {
#pragma unroll
        for (int jj = 0; jj < 16; jj++) r2[jj] = T[(jj + 16 * (j - 8)) * TWP + c];
    }
    // stages 3-4
#pragma unroll
    for (int q = 0; q < 4; q++) bf4f(r2[q], r2[q + 4], r2[q + 8], r2[q + 12], tw, 16, q);
#pragma unroll
    for (int h = 0; h < 4; h++) bf4f(r2[4 * h], r2[4 * h + 1], r2[4 * h + 2], r2[4 * h + 3], tw, 64, 0);
#pragma unroll
    for (int jj = 0; jj < 16; jj++) {
        int p = jj + 16 * j;
        int k2 = dr4(p);
        int ph = (n1 * k2) & (L - 1);
        float2 w = cmul(tw[ph >> 8], fine[ph & 255]);
        tile[(p << 6) + c] = __float22half2_rn(cmul(r2[jj], w));   // 256B per wave op
    }
}

// ---- pointwise unit (LDS form), Y scaled by PW_SCALE ----
__device__ __forceinline__ void pw_unit(float2* A, int sJ, int kJ, int sN, int kN) {
    float2 Z0j = A[sJ * ROWP + kJ],       Z0n = A[sN * ROWP + kN];
    float2 Z1j = A[(4 + sJ) * ROWP + kJ], Z1n = A[(4 + sN) * ROWP + kN];
    float2 D0 = make_float2(0.5f * (Z0j.x + Z0n.x), 0.5f * (Z0j.y - Z0n.y));
    float2 K0 = make_float2(0.5f * (Z0j.y + Z0n.y), 0.5f * (Z0n.x - Z0j.x));
    float2 D1 = make_float2(0.5f * (Z1j.x + Z1n.x), 0.5f * (Z1j.y - Z1n.y));
    float2 K1 = make_float2(0.5f * (Z1j.y + Z1n.y), 0.5f * (Z1n.x - Z1j.x));
    float2 W0 = cmul(D0, K0);
    float2 W1 = cmul(D1, K1);
    A[sJ * ROWP + kJ] = make_float2((W0.x - W1.y) * PW_SCALE, (W0.y + W1.x) * PW_SCALE);
    A[sN * ROWP + kN] = make_float2((W0.x + W1.y) * PW_SCALE, (W1.x - W0.y) * PW_SCALE);
}

// ---- fused row pass: fwd radix-4 DIF (8 rows) -> pointwise -> inv DIT (4 rows) ----
__global__ void k_rowpw(__half2* __restrict__ C) {
    __shared__ float2 A[8 * ROWP];
    __shared__ float2 tw[192];
    int t = threadIdx.x;
    int p = blockIdx.x >> 6;
    int g = blockIdx.x & 63;
    int rows[4];
    if (g == 0) { rows[0] = 0; rows[1] = 1; rows[2] = 128; rows[3] = 255; }
    else        { rows[0] = 2 * g; rows[1] = 2 * g + 1; rows[2] = 256 - 2 * g; rows[3] = 255 - 2 * g; }
    if (t < 192) {
        float sv, cv;
        __sincosf(-TWO_PI * (float)t * (1.0f / 256.0f), &sv, &cv);
        tw[t] = make_float2(cv, sv);
    }
    __half2* b0 = C + ((size_t)(2 * p) * 4) * TILE;
    __half2* b1 = b0 + 4 * TILE;
    for (int u = t; u < 512; u += 256) {
        int slot = u >> 6;               // 0..7
        int f = (u & 63) << 2;           // n1 start (multiple of 4)
        int cg = f >> 6, c2 = f & 63;
        const __half2* arr = (slot < 4) ? b0 : b1;
        int grow = dr4(rows[slot & 3]);
        float4 raw = *(const float4*)(arr + cg * TILE + (grow << 6) + c2);
        const __half2* hp = (const __half2*)&raw;
        A[slot * ROWP + f]     = __half22float2(hp[0]);
        A[slot * ROWP + f + 1] = __half22float2(hp[1]);
        A[slot * ROWP + f + 2] = __half22float2(hp[2]);
        A[slot * ROWP + f + 3] = __half22float2(hp[3]);
    }
    __syncthreads();
#pragma unroll
    for (int lm = 8; lm >= 6; lm -= 2) {
        int Q = 1 << (lm - 2), f = 256 >> lm;
        for (int u = t; u < 512; u += 256) {
            int row = u >> 6, qi = u & 63;
            int q = qi & (Q - 1);
            int i0 = ((qi - q) << 2) + q;
            bfly4_fwd(A, row * ROWP + i0, Q, tw, f, q);
        }
        __syncthreads();
    }
#pragma unroll
    for (int lm = 4; lm >= 2; lm -= 2) {
        int Q = 1 << (lm - 2), f = 256 >> lm;
        for (int u = t; u < 512; u += 256) {
            int row = u & 7, qi = u >> 3;
            int q = qi & (Q - 1);
            int i0 = ((qi - q) << 2) + q;
            bfly4_fwd(A, row * ROWP + i0, Q, tw, f, q);
        }
        __syncthreads();
    }
    if (g) {
        pw_unit(A, 0, t, 2, 255 - t);
    } else {
        if (t == 0)      { pw_unit(A, 0, 0, 0, 0); pw_unit(A, 0, 2, 0, 2); }
        else if (t < 128) pw_unit(A, 0, dr4(t), 0, dr4(256 - t));
        else              { int qq = t - 128; pw_unit(A, 2, qq, 2, 255 - qq); }
    }
    pw_unit(A, 1, t, 3, 255 - t);
    __syncthreads();
#pragma unroll
    for (int lm = 2; lm <= 4; lm += 2) {
        int Q = 1 << (lm - 2), f = 256 >> lm;
        int row = t & 3, qi = t >> 2;
        int q = qi & (Q - 1);
        int i0 = ((qi - q) << 2) + q;
        bfly4_inv(A, row * ROWP + i0, Q, tw, f, q);
        __syncthreads();
    }
#pragma unroll
    for (int lm = 6; lm <= 8; lm += 2) {
        int Q = 1 << (lm - 2), f = 256 >> lm;
        int row = t >> 6, qi = t & 63;
        int q = qi & (Q - 1);
        int i0 = ((qi - q) << 2) + q;
        bfly4_inv(A, row * ROWP + i0, Q, tw, f, q);
        __syncthreads();
    }
    {
        int u = t;                       // 256 threads: 4 slots x 64 quads
        int slot = u >> 6;               // 0..3
        int f = (u & 63) << 2;
        int cg = f >> 6, c2 = f & 63;
        int r = rows[slot];
        __half2 outv[4];
#pragma unroll
        for (int i = 0; i < 4; i++) {
            float2 v = A[slot * ROWP + f + i];
            int ph = ((f + i) * r) & (L - 1);
            float sv, cv;
            __sincosf(TWO_PI * (float)ph * INV_L, &sv, &cv);
            outv[i] = __float22half2_rn(cmul(v, make_float2(cv, sv)));
        }
        *(float4*)(b0 + cg * TILE + (dr4(r) << 6) + c2) = *(float4*)outv;
    }
}

// ---- inverse col pass: 512 threads, 32 columns; half2 tile reads; fused mix+max ----
__global__ __launch_bounds__(512) void k_colinv(const __half2* __restrict__ C,
                                                const __half* __restrict__ dryfh,
                                                const float* __restrict__ mixv,
                                                float* __restrict__ out,
                                                float* __restrict__ partial) {
    __shared__ float2 T[128 * TWP2];
    __shared__ float2 tw[256];
    __shared__ float sm0[8], sm1[8];
    int t = threadIdx.x;
    int a = blockIdx.x >> 3;       // pair
    int cgrp = blockIdx.x & 7;     // 8 x 32 columns
    int c0 = cgrp * 32;
    const __half2* tile = C + ((size_t)(2 * a * 4 + (c0 >> 6))) * TILE;
    int coff = c0 & 63;
    if (t < 256) {
        float sv, cv;
        __sincosf(-TWO_PI * (float)t * (1.0f / 256.0f), &sv, &cv);
        tw[t] = make_float2(cv, sv);
    }
    int j = t >> 5, c = t & 31;
    int n1 = c0 + c;
    float2 r[16];
#pragma unroll
    for (int jj = 0; jj < 16; jj++)
        r[jj] = __half22float2(tile[((jj + 16 * j) << 6) + coff + c]);
    __syncthreads();
#pragma unroll
    for (int h = 0; h < 4; h++) bf4i(r[4 * h], r[4 * h + 1], r[4 * h + 2], r[4 * h + 3], tw, 64, 0);
#pragma unroll
    for (int q = 0; q < 4; q++) bf4i(r[q], r[q + 4], r[q + 8], r[q + 12], tw, 16, q);
    // two-round transpose
    float2 r2[16];
    if (j < 8) {
#pragma unroll
        for (int jj = 0; jj < 16; jj++) T[(jj + 16 * j) * TWP2 + c] = r[jj];
    }
    __syncthreads();
#pragma unroll
    for (int m = 0; m < 8; m++) r2[m] = T[(j + 16 * m) * TWP2 + c];
    __syncthreads();
    if (j >= 8) {
#pragma unroll
        for (int jj = 0; jj < 16; jj++) T[(16 * (j - 8) + jj) * TWP2 + c] = r[jj];
    }
    __syncthreads();
#pragma unroll
    for (int m = 8; m < 16; m++) r2[m] = T[(j + 16 * (m - 8)) * TWP2 + c];
#pragma unroll
    for (int h = 0; h < 4; h++) bf4i(r2[4 * h], r2[4 * h + 1], r2[4 * h + 2], r2[4 * h + 3], tw, 4, j);
#pragma unroll
    for (int m0 = 0; m0 < 4; m0++) bf4i(r2[m0], r2[m0 + 4], r2[m0 + 8], r2[m0 + 12], tw, 1, j + 16 * m0);
    int b0 = 2 * a, b1 = 2 * a + 1;
    float mix0 = mixv[b0], mix1 = mixv[b1];
    float om0 = 1.f - mix0, om1 = 1.f - mix1;
    const __half* dry0 = dryfh + (size_t)b0 * N_T;
    const __half* dry1 = dryfh + (size_t)b1 * N_T;
    float* out0 = out + (size_t)b0 * N_T;
    float* out1 = out + (size_t)b1 * N_T;
    float m0 = -3.4e38f, m1 = -3.4e38f;
#pragma unroll
    for (int m = 0; m < 8; m++) {
        int pos = n1 + ((j + 16 * m) << 8);      // n2 = j+16m < 128
        float d0 = __half2float(dry0[pos]), d1 = __half2float(dry1[pos]);
        float o0 = mix0 * (r2[m].x * COL_SCALE) + om0 * d0;
        float o1 = mix1 * (r2[m].y * COL_SCALE) + om1 * d1;
        out0[pos] = o0;
        out1[pos] = o1;
        m0 = fmaxf(m0, o0);
        m1 = fmaxf(m1, o1);
    }
#pragma unroll
    for (int off = 32; off > 0; off >>= 1) {
        m0 = fmaxf(m0, __shfl_down(m0, off));
        m1 = fmaxf(m1, __shfl_down(m1, off));
    }
    if ((t & 63) == 0) { sm0[t >> 6] = m0; sm1[t >> 6] = m1; }
    __syncthreads();
    if (t == 0) {
        float p0 = sm0[0], p1 = sm1[0];
#pragma unroll
        for (int w = 1; w < 8; w++) { p0 = fmaxf(p0, sm0[w]); p1 = fmaxf(p1, sm1[w]); }
        partial[b0 * 8 + cgrp] = p0;
        partial[b1 * 8 + cgrp] = p1;
    }
}

__global__ void k_norm(float* __restrict__ out, const float* __restrict__ partial) {
    int blk = blockIdx.x;
    int b = blk >> 5;
    int ch = blk & 31;
    __shared__ float smx;
    if (threadIdx.x < 8) {
        float p = partial[b * 8 + threadIdx.x];
#pragma unroll
        for (int off = 4; off > 0; off >>= 1) p = fmaxf(p, __shfl_down(p, off, 8));
        if (threadIdx.x == 0) smx = p;
    }
    __syncthreads();
    float inv = 1.f / (smx + 1e-8f);
    size_t base = (size_t)b * N_T + ch * 1024 + threadIdx.x * 4;
    float4 o = *(const float4*)(out + base);
    o.x *= inv; o.y *= inv; o.z *= inv; o.w *= inv;
    *(float4*)(out + base) = o;
}

extern "C" void kernel_launch(void* const* d_in, const int* in_sizes, int n_in,
                              void* d_out, int out_size, void* d_ws, size_t ws_size,
                              hipStream_t stream) {
    const float* events = (const float*)d_in[0];
    const int* indices = (const int*)d_in[1];
    const float* g      = (const float*)d_in[2];
    const float* rooms  = (const float*)d_in[3];
    const float* w_room = (const float*)d_in[4];
    const float* b_room = (const float*)d_in[5];
    const float* w_mix  = (const float*)d_in[6];
    const float* b_mix  = (const float*)d_in[7];
    float* out = (float*)d_out;

    char* ws = (char*)d_ws;
    __half2* C = (__half2*)ws;               // [64 batches][4 tiles][256 p][64 c] half2 = 16 MB
    size_t off = (size_t)BATCH * L * sizeof(__half2);
    __half* dryfh = (__half*)(ws + off);     // 4 MB
    off += (size_t)BATCH * N_T * sizeof(__half);
    float* wroom = (float*)(ws + off);
    off += BATCH * NROOM * sizeof(float);
    float* mixv = (float*)(ws + off);
    off += BATCH * sizeof(float);
    float* partial = (float*)(ws + off);

    k_prep<<<1, 64, 0, stream>>>(g, w_room, b_room, w_mix, b_mix, wroom, mixv);
    k_fwd<<<BATCH * 4, 1024, 0, stream>>>(events, indices, rooms, wroom, dryfh, C);
    k_rowpw<<<NPAIR * 64, 256, 0, stream>>>(C);
    k_colinv<<<NPAIR * 8, 512, 0, stream>>>(C, dryfh, mixv, out, partial);
    k_norm<<<BATCH * 32, 256, 0, stream>>>(out, partial);
}

// Round 17
// 56.890 us; speedup vs baseline: 1.9740x; 1.2471x over previous
//
#include <hip/hip_runtime.h>
#include <hip/hip_fp16.h>
#include <math.h>

#define N_T 32768
#define L 65536
#define BATCH 64
#define NPAIR 32
#define NEV 8
#define NROOM 16
#define DGATE 128
#define ROWP 258
#define TWP 65                 // k_fwd transpose pad (64 cols)
#define TWP2 33                // colinv transpose pad (32 cols)
#define TILE 16384             // half2 elements per C tile: [256 p][64 c]
#define TWO_PI 6.2831853071795864769f
#define INV_L (1.0f / 65536.0f)
#define PW_SCALE (1.0f / 256.0f)   // half of 1/L folded at pointwise
#define COL_SCALE (1.0f / 256.0f)  // other half at colinv

__device__ __forceinline__ float2 cmul(float2 a, float2 b) {
    return make_float2(a.x * b.x - a.y * b.y, a.x * b.y + a.y * b.x);
}
// base-4 digit reversal of an 8-bit index (involution)
__device__ __forceinline__ int dr4(int p) {
    return ((p & 3) << 6) | ((p & 12) << 2) | ((p & 48) >> 2) | ((p & 192) >> 6);
}

// register radix-4 DIF butterfly (fwd)
__device__ __forceinline__ void bf4f(float2& a, float2& b, float2& c, float2& d,
                                     const float2* tw, int f, int q) {
    float2 t0 = make_float2(a.x + c.x, a.y + c.y);
    float2 t1 = make_float2(a.x - c.x, a.y - c.y);
    float2 t2 = make_float2(b.x + d.x, b.y + d.y);
    float2 u  = make_float2(b.x - d.x, b.y - d.y);
    float2 t3 = make_float2(u.y, -u.x);            // -i*u
    a = make_float2(t0.x + t2.x, t0.y + t2.y);
    b = cmul(make_float2(t1.x + t3.x, t1.y + t3.y), tw[f * q]);
    c = cmul(make_float2(t0.x - t2.x, t0.y - t2.y), tw[2 * f * q]);
    d = cmul(make_float2(t1.x - t3.x, t1.y - t3.y), tw[3 * f * q]);
}
// register radix-4 DIT butterfly (inv): exact inverse of bf4f
__device__ __forceinline__ void bf4i(float2& a, float2& b, float2& c, float2& d,
                                     const float2* tw, int f, int q) {
    float2 w1 = tw[f * q], w2 = tw[2 * f * q], w3 = tw[3 * f * q];
    float2 y0 = a;
    float2 y1 = cmul(b, make_float2(w1.x, -w1.y));
    float2 y2 = cmul(c, make_float2(w2.x, -w2.y));
    float2 y3 = cmul(d, make_float2(w3.x, -w3.y));
    float2 t0 = make_float2(y0.x + y2.x, y0.y + y2.y);
    float2 t2 = make_float2(y0.x - y2.x, y0.y - y2.y);
    float2 t1 = make_float2(y1.x + y3.x, y1.y + y3.y);
    float2 u  = make_float2(y1.x - y3.x, y1.y - y3.y);
    a = make_float2(t0.x + t1.x, t0.y + t1.y);
    b = make_float2(t2.x - u.y, t2.y + u.x);
    c = make_float2(t0.x - t1.x, t0.y - t1.y);
    d = make_float2(t2.x + u.y, t2.y - u.x);
}
__device__ __forceinline__ void bfly4_fwd(float2* A, int a0, int st, const float2* tw, int f, int q) {
    bf4f(A[a0], A[a0 + st], A[a0 + 2 * st], A[a0 + 3 * st], tw, f, q);
}
__device__ __forceinline__ void bfly4_inv(float2* A, int a0, int st, const float2* tw, int f, int q) {
    bf4i(A[a0], A[a0 + st], A[a0 + 2 * st], A[a0 + 3 * st], tw, f, q);
}

// ---- fused wide col pass: inline gating, stage dry+K (64 cols), write dryf (fp16),
// radix-4 fwd FFT, big twiddle, store C tile as half2 ----
__global__ __launch_bounds__(1024) void k_fwd(const float* __restrict__ events,
                                              const int* __restrict__ indices,
                                              const float* __restrict__ rooms,
                                              const float* __restrict__ g,
                                              const float* __restrict__ w_room,
                                              const float* __restrict__ b_room,
                                              __half* __restrict__ dryfh,
                                              __half2* __restrict__ C) {
    __shared__ float2 T[128 * TWP];      // 66.5 KB; front 64 KB doubles as dry/K staging
    __shared__ float2 tw[256];
    __shared__ float2 fine[256];
    __shared__ float wr_s[NROOM];
    int t = threadIdx.x;
    int a = blockIdx.x >> 2;             // batch
    int cg = blockIdx.x & 3;             // column group (4 x 64)
    int c0 = cg * 64;
    __half2* tile = C + ((size_t)(a * 4 + cg)) * TILE;
    if (t < 256) {
        float sv, cv;
        __sincosf(-TWO_PI * (float)t * (1.0f / 256.0f), &sv, &cv);
        tw[t] = make_float2(cv, sv);
        __sincosf(-TWO_PI * (float)t * INV_L, &sv, &cv);
        fine[t] = make_float2(cv, sv);
    }
    // inline gating: 16 threads compute logits, thread 0 softmaxes
    if (t >= 256 && t < 256 + NROOM) {
        int r = t - 256;
        const float* gb = g + a * DGATE;
        float acc = b_room[r];
        for (int d = 0; d < DGATE; d++) acc += gb[d] * w_room[d * NROOM + r];
        wr_s[r] = acc;
    }
    __syncthreads();
    if (t == 0) {
        float m = wr_s[0];
        for (int r = 1; r < NROOM; r++) m = fmaxf(m, wr_s[r]);
        float e[NROOM];
        float s = 0.f;
        for (int r = 0; r < NROOM; r++) { e[r] = expf(wr_s[r] - m); s += e[r]; }
        float inv = 1.f / s;
        for (int r = 0; r < NROOM; r++) wr_s[r] = e[r] * inv;
    }
    __syncthreads();
    float* dtile = (float*)T;            // [128][64] dry (32 KB)
    float* ktile = dtile + 128 * 64;     // [128][64] K   (32 KB)
    {
        int n2 = t >> 3;                 // 0..127
        int cc = (t & 7) << 3;           // 0..56
        const float* eb = events + (size_t)a * NEV * N_T;
        const int* ib = indices + a * NEV;
        float4 dA = make_float4(0.f, 0.f, 0.f, 0.f), dB = dA;
#pragma unroll
        for (int e = 0; e < NEV; e++) {
            int s = ib[e];
            if (n2 >= s) {
                const float* er = eb + e * N_T + ((n2 - s) << 8) + c0 + cc;
                float4 vA = *(const float4*)er;
                float4 vB = *(const float4*)(er + 4);
                dA.x += vA.x; dA.y += vA.y; dA.z += vA.z; dA.w += vA.w;
                dB.x += vB.x; dB.y += vB.y; dB.z += vB.z; dB.w += vB.w;
            }
        }
        float4 kA = make_float4(0.f, 0.f, 0.f, 0.f), kB = kA;
#pragma unroll
        for (int r = 0; r < NROOM; r++) {
            float w = wr_s[r];
            const float* rr = rooms + (size_t)r * N_T + (n2 << 8) + c0 + cc;
            float4 vA = *(const float4*)rr;
            float4 vB = *(const float4*)(rr + 4);
            kA.x += w * vA.x; kA.y += w * vA.y; kA.z += w * vA.z; kA.w += w * vA.w;
            kB.x += w * vB.x; kB.y += w * vB.y; kB.z += w * vB.z; kB.w += w * vB.w;
        }
        __half2 hd[4];
        hd[0] = __float22half2_rn(make_float2(dA.x, dA.y));
        hd[1] = __float22half2_rn(make_float2(dA.z, dA.w));
        hd[2] = __float22half2_rn(make_float2(dB.x, dB.y));
        hd[3] = __float22half2_rn(make_float2(dB.z, dB.w));
        *(float4*)(dryfh + (size_t)a * N_T + (n2 << 8) + c0 + cc) = *(float4*)hd;
        *(float4*)&dtile[(n2 << 6) + cc] = dA;
        *(float4*)&dtile[(n2 << 6) + cc + 4] = dB;
        *(float4*)&ktile[(n2 << 6) + cc] = kA;
        *(float4*)&ktile[(n2 << 6) + cc + 4] = kB;
    }
    __syncthreads();
    int j = t >> 6, c = t & 63;
    int n1 = c0 + c;
    float2 r[16];
#pragma unroll
    for (int m = 0; m < 8; m++) {
        int n2 = j + 16 * m;             // < 128 always
        r[m] = make_float2(dtile[(n2 << 6) + c], ktile[(n2 << 6) + c]);
    }
#pragma unroll
    for (int m = 8; m < 16; m++) r[m] = make_float2(0.f, 0.f);
    // stages 1-2 in registers
#pragma unroll
    for (int m0 = 0; m0 < 4; m0++) bf4f(r[m0], r[m0 + 4], r[m0 + 8], r[m0 + 12], tw, 1, j + 16 * m0);
#pragma unroll
    for (int h = 0; h < 4; h++) bf4f(r[4 * h], r[4 * h + 1], r[4 * h + 2], r[4 * h + 3], tw, 4, j);
    __syncthreads();                     // staging reads done; T reusable
    // two-round transpose through 128-row buffer
    float2 r2[16];
#pragma unroll
    for (int m = 0; m < 8; m++) T[(j + 16 * m) * TWP + c] = r[m];
    __syncthreads();
    if (j < 8) {
#pragma unroll
        for (int jj = 0; jj < 16; jj++) r2[jj] = T[(jj + 16 * j) * TWP + c];
    }
    __syncthreads();
#pragma unroll
    for (int m = 8; m < 16; m++) T[(j + 16 * m - 128) * TWP + c] = r[m];
    __syncthreads();
    if (j >= 8) {
#pragma unroll
        for (int jj = 0; jj < 16; jj++) r2[jj] = T[(jj + 16 * (j - 8)) * TWP + c];
    }
    // stages 3-4
#pragma unroll
    for (int q = 0; q < 4; q++) bf4f(r2[q], r2[q + 4], r2[q + 8], r2[q + 12], tw, 16, q);
#pragma unroll
    for (int h = 0; h < 4; h++) bf4f(r2[4 * h], r2[4 * h + 1], r2[4 * h + 2], r2[4 * h + 3], tw, 64, 0);
#pragma unroll
    for (int jj = 0; jj < 16; jj++) {
        int p = jj + 16 * j;
        int k2 = dr4(p);
        int ph = (n1 * k2) & (L - 1);
        float2 w = cmul(tw[ph >> 8], fine[ph & 255]);
        tile[(p << 6) + c] = __float22half2_rn(cmul(r2[jj], w));
    }
}

// ---- pointwise unit (LDS form), Y scaled by PW_SCALE ----
__device__ __forceinline__ void pw_unit(float2* A, int sJ, int kJ, int sN, int kN) {
    float2 Z0j = A[sJ * ROWP + kJ],       Z0n = A[sN * ROWP + kN];
    float2 Z1j = A[(4 + sJ) * ROWP + kJ], Z1n = A[(4 + sN) * ROWP + kN];
    float2 D0 = make_float2(0.5f * (Z0j.x + Z0n.x), 0.5f * (Z0j.y - Z0n.y));
    float2 K0 = make_float2(0.5f * (Z0j.y + Z0n.y), 0.5f * (Z0n.x - Z0j.x));
    float2 D1 = make_float2(0.5f * (Z1j.x + Z1n.x), 0.5f * (Z1j.y - Z1n.y));
    float2 K1 = make_float2(0.5f * (Z1j.y + Z1n.y), 0.5f * (Z1n.x - Z1j.x));
    float2 W0 = cmul(D0, K0);
    float2 W1 = cmul(D1, K1);
    A[sJ * ROWP + kJ] = make_float2((W0.x - W1.y) * PW_SCALE, (W0.y + W1.x) * PW_SCALE);
    A[sN * ROWP + kN] = make_float2((W0.x + W1.y) * PW_SCALE, (W1.x - W0.y) * PW_SCALE);
}

// ---- fused row pass: fwd radix-4 DIF (8 rows) -> pointwise -> inv DIT (4 rows) ----
__global__ void k_rowpw(__half2* __restrict__ C) {
    __shared__ float2 A[8 * ROWP];
    __shared__ float2 tw[192];
    int t = threadIdx.x;
    int p = blockIdx.x >> 6;
    int g = blockIdx.x & 63;
    int rows[4];
    if (g == 0) { rows[0] = 0; rows[1] = 1; rows[2] = 128; rows[3] = 255; }
    else        { rows[0] = 2 * g; rows[1] = 2 * g + 1; rows[2] = 256 - 2 * g; rows[3] = 255 - 2 * g; }
    if (t < 192) {
        float sv, cv;
        __sincosf(-TWO_PI * (float)t * (1.0f / 256.0f), &sv, &cv);
        tw[t] = make_float2(cv, sv);
    }
    __half2* b0 = C + ((size_t)(2 * p) * 4) * TILE;
    __half2* b1 = b0 + 4 * TILE;
    for (int u = t; u < 512; u += 256) {
        int slot = u >> 6;               // 0..7
        int f = (u & 63) << 2;           // n1 start (multiple of 4)
        int cg = f >> 6, c2 = f & 63;
        const __half2* arr = (slot < 4) ? b0 : b1;
        int grow = dr4(rows[slot & 3]);
        float4 raw = *(const float4*)(arr + cg * TILE + (grow << 6) + c2);
        const __half2* hp = (const __half2*)&raw;
        A[slot * ROWP + f]     = __half22float2(hp[0]);
        A[slot * ROWP + f + 1] = __half22float2(hp[1]);
        A[slot * ROWP + f + 2] = __half22float2(hp[2]);
        A[slot * ROWP + f + 3] = __half22float2(hp[3]);
    }
    __syncthreads();
#pragma unroll
    for (int lm = 8; lm >= 6; lm -= 2) {
        int Q = 1 << (lm - 2), f = 256 >> lm;
        for (int u = t; u < 512; u += 256) {
            int row = u >> 6, qi = u & 63;
            int q = qi & (Q - 1);
            int i0 = ((qi - q) << 2) + q;
            bfly4_fwd(A, row * ROWP + i0, Q, tw, f, q);
        }
        __syncthreads();
    }
#pragma unroll
    for (int lm = 4; lm >= 2; lm -= 2) {
        int Q = 1 << (lm - 2), f = 256 >> lm;
        for (int u = t; u < 512; u += 256) {
            int row = u & 7, qi = u >> 3;
            int q = qi & (Q - 1);
            int i0 = ((qi - q) << 2) + q;
            bfly4_fwd(A, row * ROWP + i0, Q, tw, f, q);
        }
        __syncthreads();
    }
    if (g) {
        pw_unit(A, 0, t, 2, 255 - t);
    } else {
        if (t == 0)      { pw_unit(A, 0, 0, 0, 0); pw_unit(A, 0, 2, 0, 2); }
        else if (t < 128) pw_unit(A, 0, dr4(t), 0, dr4(256 - t));
        else              { int qq = t - 128; pw_unit(A, 2, qq, 2, 255 - qq); }
    }
    pw_unit(A, 1, t, 3, 255 - t);
    __syncthreads();
#pragma unroll
    for (int lm = 2; lm <= 4; lm += 2) {
        int Q = 1 << (lm - 2), f = 256 >> lm;
        int row = t & 3, qi = t >> 2;
        int q = qi & (Q - 1);
        int i0 = ((qi - q) << 2) + q;
        bfly4_inv(A, row * ROWP + i0, Q, tw, f, q);
        __syncthreads();
    }
#pragma unroll
    for (int lm = 6; lm <= 8; lm += 2) {
        int Q = 1 << (lm - 2), f = 256 >> lm;
        int row = t >> 6, qi = t & 63;
        int q = qi & (Q - 1);
        int i0 = ((qi - q) << 2) + q;
        bfly4_inv(A, row * ROWP + i0, Q, tw, f, q);
        __syncthreads();
    }
    {
        int u = t;                       // 256 threads: 4 slots x 64 quads
        int slot = u >> 6;               // 0..3
        int f = (u & 63) << 2;
        int cg = f >> 6, c2 = f & 63;
        int r = rows[slot];
        __half2 outv[4];
#pragma unroll
        for (int i = 0; i < 4; i++) {
            float2 v = A[slot * ROWP + f + i];
            int ph = ((f + i) * r) & (L - 1);
            float sv, cv;
            __sincosf(TWO_PI * (float)ph * INV_L, &sv, &cv);
            outv[i] = __float22half2_rn(cmul(v, make_float2(cv, sv)));
        }
        *(float4*)(b0 + cg * TILE + (dr4(r) << 6) + c2) = *(float4*)outv;
    }
}

// ---- inverse col pass: inline mix-gate, half2 tile reads, fp16 mixed output + max ----
__global__ __launch_bounds__(512) void k_colinv(const __half2* __restrict__ C,
                                                const __half* __restrict__ dryfh,
                                                const float* __restrict__ g,
                                                const float* __restrict__ w_mix,
                                                const float* __restrict__ b_mix,
                                                __half* __restrict__ mixo,
                                                float* __restrict__ partial) {
    __shared__ float2 T[128 * TWP2];
    __shared__ float2 tw[256];
    __shared__ float sm0[8], sm1[8];
    __shared__ float smix[2];
    int t = threadIdx.x;
    int a = blockIdx.x >> 3;       // pair
    int cgrp = blockIdx.x & 7;     // 8 x 32 columns
    int c0 = cgrp * 32;
    const __half2* tile = C + ((size_t)(2 * a * 4 + (c0 >> 6))) * TILE;
    int coff = c0 & 63;
    if (t < 256) {
        float sv, cv;
        __sincosf(-TWO_PI * (float)t * (1.0f / 256.0f), &sv, &cv);
        tw[t] = make_float2(cv, sv);
    }
    if (t >= 256 && t < 258) {
        int bb = 2 * a + (t - 256);
        const float* gb = g + bb * DGATE;
        float acc = b_mix[0];
        for (int d = 0; d < DGATE; d++) acc += gb[d] * w_mix[d];
        smix[t - 256] = 1.f / (1.f + expf(-acc));
    }
    int j = t >> 5, c = t & 31;
    int n1 = c0 + c;
    float2 r[16];
#pragma unroll
    for (int jj = 0; jj < 16; jj++)
        r[jj] = __half22float2(tile[((jj + 16 * j) << 6) + coff + c]);
    __syncthreads();
#pragma unroll
    for (int h = 0; h < 4; h++) bf4i(r[4 * h], r[4 * h + 1], r[4 * h + 2], r[4 * h + 3], tw, 64, 0);
#pragma unroll
    for (int q = 0; q < 4; q++) bf4i(r[q], r[q + 4], r[q + 8], r[q + 12], tw, 16, q);
    // two-round transpose
    float2 r2[16];
    if (j < 8) {
#pragma unroll
        for (int jj = 0; jj < 16; jj++) T[(jj + 16 * j) * TWP2 + c] = r[jj];
    }
    __syncthreads();
#pragma unroll
    for (int m = 0; m < 8; m++) r2[m] = T[(j + 16 * m) * TWP2 + c];
    __syncthreads();
    if (j >= 8) {
#pragma unroll
        for (int jj = 0; jj < 16; jj++) T[(16 * (j - 8) + jj) * TWP2 + c] = r[jj];
    }
    __syncthreads();
#pragma unroll
    for (int m = 8; m < 16; m++) r2[m] = T[(j + 16 * (m - 8)) * TWP2 + c];
#pragma unroll
    for (int h = 0; h < 4; h++) bf4i(r2[4 * h], r2[4 * h + 1], r2[4 * h + 2], r2[4 * h + 3], tw, 4, j);
#pragma unroll
    for (int m0 = 0; m0 < 4; m0++) bf4i(r2[m0], r2[m0 + 4], r2[m0 + 8], r2[m0 + 12], tw, 1, j + 16 * m0);
    int b0 = 2 * a, b1 = 2 * a + 1;
    float mix0 = smix[0], mix1 = smix[1];
    float om0 = 1.f - mix0, om1 = 1.f - mix1;
    const __half* dry0 = dryfh + (size_t)b0 * N_T;
    const __half* dry1 = dryfh + (size_t)b1 * N_T;
    __half* mo0 = mixo + (size_t)b0 * N_T;
    __half* mo1 = mixo + (size_t)b1 * N_T;
    float m0 = -3.4e38f, m1 = -3.4e38f;
#pragma unroll
    for (int m = 0; m < 8; m++) {
        int pos = n1 + ((j + 16 * m) << 8);      // n2 = j+16m < 128
        float d0 = __half2float(dry0[pos]), d1 = __half2float(dry1[pos]);
        float o0 = mix0 * (r2[m].x * COL_SCALE) + om0 * d0;
        float o1 = mix1 * (r2[m].y * COL_SCALE) + om1 * d1;
        mo0[pos] = __float2half(o0);
        mo1[pos] = __float2half(o1);
        m0 = fmaxf(m0, o0);
        m1 = fmaxf(m1, o1);
    }
#pragma unroll
    for (int off = 32; off > 0; off >>= 1) {
        m0 = fmaxf(m0, __shfl_down(m0, off));
        m1 = fmaxf(m1, __shfl_down(m1, off));
    }
    if ((t & 63) == 0) { sm0[t >> 6] = m0; sm1[t >> 6] = m1; }
    __syncthreads();
    if (t == 0) {
        float p0 = sm0[0], p1 = sm1[0];
#pragma unroll
        for (int w = 1; w < 8; w++) { p0 = fmaxf(p0, sm0[w]); p1 = fmaxf(p1, sm1[w]); }
        partial[b0 * 8 + cgrp] = p0;
        partial[b1 * 8 + cgrp] = p1;
    }
}

// ---- normalize: read fp16 mixed output, divide by row max, write fp32 out ----
__global__ void k_norm(const __half* __restrict__ mixo, const float* __restrict__ partial,
                       float* __restrict__ out) {
    int blk = blockIdx.x;
    int b = blk >> 5;
    int ch = blk & 31;
    __shared__ float smx;
    if (threadIdx.x < 8) {
        float p = partial[b * 8 + threadIdx.x];
#pragma unroll
        for (int off = 4; off > 0; off >>= 1) p = fmaxf(p, __shfl_down(p, off, 8));
        if (threadIdx.x == 0) smx = p;
    }
    __syncthreads();
    float inv = 1.f / (smx + 1e-8f);
    size_t base = (size_t)b * N_T + ch * 1024 + threadIdx.x * 4;
    float2 hraw = *(const float2*)(mixo + base);   // 4 halves
    const __half2* hp = (const __half2*)&hraw;
    float2 v0 = __half22float2(hp[0]);
    float2 v1 = __half22float2(hp[1]);
    float4 o = make_float4(v0.x * inv, v0.y * inv, v1.x * inv, v1.y * inv);
    *(float4*)(out + base) = o;
}

extern "C" void kernel_launch(void* const* d_in, const int* in_sizes, int n_in,
                              void* d_out, int out_size, void* d_ws, size_t ws_size,
                              hipStream_t stream) {
    const float* events = (const float*)d_in[0];
    const int* indices = (const int*)d_in[1];
    const float* g      = (const float*)d_in[2];
    const float* rooms  = (const float*)d_in[3];
    const float* w_room = (const float*)d_in[4];
    const float* b_room = (const float*)d_in[5];
    const float* w_mix  = (const float*)d_in[6];
    const float* b_mix  = (const float*)d_in[7];
    float* out = (float*)d_out;

    char* ws = (char*)d_ws;
    __half2* C = (__half2*)ws;               // [64 batches][4 tiles][256 p][64 c] half2 = 16 MB
    size_t off = (size_t)BATCH * L * sizeof(__half2);
    __half* dryfh = (__half*)(ws + off);     // 4 MB
    off += (size_t)BATCH * N_T * sizeof(__half);
    __half* mixo = (__half*)(ws + off);      // 4 MB
    off += (size_t)BATCH * N_T * sizeof(__half);
    float* partial = (float*)(ws + off);

    k_fwd<<<BATCH * 4, 1024, 0, stream>>>(events, indices, rooms, g, w_room, b_room, dryfh, C);
    k_rowpw<<<NPAIR * 64, 256, 0, stream>>>(C);
    k_colinv<<<NPAIR * 8, 512, 0, stream>>>(C, dryfh, g, w_mix, b_mix, mixo, partial);
    k_norm<<<BATCH * 32, 256, 0, stream>>>(mixo, partial, out);
}

// Round 18
// 54.308 us; speedup vs baseline: 2.0679x; 1.0475x over previous
//
#include <hip/hip_runtime.h>
#include <hip/hip_fp16.h>
#include <math.h>

#define N_T 32768
#define L 65536
#define BATCH 64
#define NPAIR 32
#define NEV 8
#define NROOM 16
#define DGATE 128
#define ROWP 258
#define TP32 33                // transpose pad (32 cols)
#define TILE32 8192            // half2 per C tile: [256 p][32 c]
#define TWO_PI 6.2831853071795864769f
#define INV_L (1.0f / 65536.0f)
#define PW_SCALE (1.0f / 256.0f)
#define COL_SCALE (1.0f / 256.0f)

__device__ __forceinline__ float2 cmul(float2 a, float2 b) {
    return make_float2(a.x * b.x - a.y * b.y, a.x * b.y + a.y * b.x);
}
__device__ __forceinline__ int dr4(int p) {
    return ((p & 3) << 6) | ((p & 12) << 2) | ((p & 48) >> 2) | ((p & 192) >> 6);
}

__device__ __forceinline__ void bf4f(float2& a, float2& b, float2& c, float2& d,
                                     const float2* tw, int f, int q) {
    float2 t0 = make_float2(a.x + c.x, a.y + c.y);
    float2 t1 = make_float2(a.x - c.x, a.y - c.y);
    float2 t2 = make_float2(b.x + d.x, b.y + d.y);
    float2 u  = make_float2(b.x - d.x, b.y - d.y);
    float2 t3 = make_float2(u.y, -u.x);
    a = make_float2(t0.x + t2.x, t0.y + t2.y);
    b = cmul(make_float2(t1.x + t3.x, t1.y + t3.y), tw[f * q]);
    c = cmul(make_float2(t0.x - t2.x, t0.y - t2.y), tw[2 * f * q]);
    d = cmul(make_float2(t1.x - t3.x, t1.y - t3.y), tw[3 * f * q]);
}
__device__ __forceinline__ void bf4i(float2& a, float2& b, float2& c, float2& d,
                                     const float2* tw, int f, int q) {
    float2 w1 = tw[f * q], w2 = tw[2 * f * q], w3 = tw[3 * f * q];
    float2 y0 = a;
    float2 y1 = cmul(b, make_float2(w1.x, -w1.y));
    float2 y2 = cmul(c, make_float2(w2.x, -w2.y));
    float2 y3 = cmul(d, make_float2(w3.x, -w3.y));
    float2 t0 = make_float2(y0.x + y2.x, y0.y + y2.y);
    float2 t2 = make_float2(y0.x - y2.x, y0.y - y2.y);
    float2 t1 = make_float2(y1.x + y3.x, y1.y + y3.y);
    float2 u  = make_float2(y1.x - y3.x, y1.y - y3.y);
    a = make_float2(t0.x + t1.x, t0.y + t1.y);
    b = make_float2(t2.x - u.y, t2.y + u.x);
    c = make_float2(t0.x - t1.x, t0.y - t1.y);
    d = make_float2(t2.x + u.y, t2.y - u.x);
}
__device__ __forceinline__ void bfly4_fwd(float2* A, int a0, int st, const float2* tw, int f, int q) {
    bf4f(A[a0], A[a0 + st], A[a0 + 2 * st], A[a0 + 3 * st], tw, f, q);
}
__device__ __forceinline__ void bfly4_inv(float2* A, int a0, int st, const float2* tw, int f, int q) {
    bf4i(A[a0], A[a0 + st], A[a0 + 2 * st], A[a0 + 3 * st], tw, f, q);
}

// ---- fused col pass: parallel inline gating, stage dry+K (32 cols), fp16 dryf,
// radix-4 fwd FFT, big twiddle, half2 tile store. 512 threads, 512 blocks (2/CU). ----
__global__ __launch_bounds__(512) void k_fwd(const float* __restrict__ events,
                                             const int* __restrict__ indices,
                                             const float* __restrict__ rooms,
                                             const float* __restrict__ g,
                                             const float* __restrict__ w_room,
                                             const float* __restrict__ b_room,
                                             __half* __restrict__ dryfh,
                                             __half2* __restrict__ C) {
    __shared__ float2 T[128 * TP32];     // 33.8 KB; front 32 KB doubles as dry/K staging
    __shared__ float2 tw[256];
    __shared__ float2 fine[256];
    __shared__ float gpart[256];
    __shared__ float wr_s[NROOM];
    int t = threadIdx.x;
    int a = blockIdx.x >> 3;             // batch
    int cg = blockIdx.x & 7;             // column group (8 x 32)
    int c0 = cg * 32;
    __half2* tile = C + ((size_t)(a * 8 + cg)) * TILE32;
    if (t < 256) {
        float sv, cv;
        __sincosf(-TWO_PI * (float)t * (1.0f / 256.0f), &sv, &cv);
        tw[t] = make_float2(cv, sv);
        __sincosf(-TWO_PI * (float)t * INV_L, &sv, &cv);
        fine[t] = make_float2(cv, sv);
        // gating partials: r = t&15, chunk = t>>4 covers 8 d's
        int r = t & 15, ch = t >> 4;
        const float* gb = g + a * DGATE + ch * 8;
        const float* wr = w_room + ch * 8 * NROOM + r;
        float acc = 0.f;
#pragma unroll
        for (int i = 0; i < 8; i++) acc += gb[i] * wr[i * NROOM];
        gpart[t] = acc;
    }
    float* dtile = (float*)T;            // [128][32] dry (16 KB)
    float* ktile = dtile + 128 * 32;     // [128][32] K   (16 KB)
    // events accumulate (independent of gating)
    int n2 = t >> 2, cc = (t & 3) << 3;
    float4 dA = make_float4(0.f, 0.f, 0.f, 0.f), dB = dA;
    {
        const float* eb = events + (size_t)a * NEV * N_T;
        const int* ib = indices + a * NEV;
#pragma unroll
        for (int e = 0; e < NEV; e++) {
            int s = ib[e];
            if (n2 >= s) {
                const float* er = eb + e * N_T + ((n2 - s) << 8) + c0 + cc;
                float4 vA = *(const float4*)er;
                float4 vB = *(const float4*)(er + 4);
                dA.x += vA.x; dA.y += vA.y; dA.z += vA.z; dA.w += vA.w;
                dB.x += vB.x; dB.y += vB.y; dB.z += vB.z; dB.w += vB.w;
            }
        }
        __half2 hd[4];
        hd[0] = __float22half2_rn(make_float2(dA.x, dA.y));
        hd[1] = __float22half2_rn(make_float2(dA.z, dA.w));
        hd[2] = __float22half2_rn(make_float2(dB.x, dB.y));
        hd[3] = __float22half2_rn(make_float2(dB.z, dB.w));
        *(float4*)(dryfh + (size_t)a * N_T + (n2 << 8) + c0 + cc) = *(float4*)hd;
        *(float4*)&dtile[(n2 << 5) + cc] = dA;
        *(float4*)&dtile[(n2 << 5) + cc + 4] = dB;
    }
    __syncthreads();                     // gpart + dtile ready
    if (t < 16) {
        float s = b_room[t];
#pragma unroll
        for (int ch = 0; ch < 16; ch++) s += gpart[ch * 16 + t];
        wr_s[t] = s;
    }
    __syncthreads();
    if (t == 0) {
        float m = wr_s[0];
        for (int r = 1; r < NROOM; r++) m = fmaxf(m, wr_s[r]);
        float e[NROOM], s = 0.f;
        for (int r = 0; r < NROOM; r++) { e[r] = expf(wr_s[r] - m); s += e[r]; }
        float inv = 1.f / s;
        for (int r = 0; r < NROOM; r++) wr_s[r] = e[r] * inv;
    }
    __syncthreads();                     // wr_s final
    {
        float4 kA = make_float4(0.f, 0.f, 0.f, 0.f), kB = kA;
#pragma unroll
        for (int r = 0; r < NROOM; r++) {
            float w = wr_s[r];
            const float* rr = rooms + (size_t)r * N_T + (n2 << 8) + c0 + cc;
            float4 vA = *(const float4*)rr;
            float4 vB = *(const float4*)(rr + 4);
            kA.x += w * vA.x; kA.y += w * vA.y; kA.z += w * vA.z; kA.w += w * vA.w;
            kB.x += w * vB.x; kB.y += w * vB.y; kB.z += w * vB.z; kB.w += w * vB.w;
        }
        *(float4*)&ktile[(n2 << 5) + cc] = kA;
        *(float4*)&ktile[(n2 << 5) + cc + 4] = kB;
    }
    __syncthreads();                     // tiles complete
    int j = t >> 5, c = t & 31;
    int n1 = c0 + c;
    float2 r[16];
#pragma unroll
    for (int m = 0; m < 8; m++) {
        int nn = j + 16 * m;             // < 128
        r[m] = make_float2(dtile[(nn << 5) + c], ktile[(nn << 5) + c]);
    }
#pragma unroll
    for (int m = 8; m < 16; m++) r[m] = make_float2(0.f, 0.f);
#pragma unroll
    for (int m0 = 0; m0 < 4; m0++) bf4f(r[m0], r[m0 + 4], r[m0 + 8], r[m0 + 12], tw, 1, j + 16 * m0);
#pragma unroll
    for (int h = 0; h < 4; h++) bf4f(r[4 * h], r[4 * h + 1], r[4 * h + 2], r[4 * h + 3], tw, 4, j);
    __syncthreads();                     // staging reads done; T reusable
    float2 r2[16];
#pragma unroll
    for (int m = 0; m < 8; m++) T[(j + 16 * m) * TP32 + c] = r[m];
    __syncthreads();
    if (j < 8) {
#pragma unroll
        for (int jj = 0; jj < 16; jj++) r2[jj] = T[(jj + 16 * j) * TP32 + c];
    }
    __syncthreads();
#pragma unroll
    for (int m = 8; m < 16; m++) T[(j + 16 * m - 128) * TP32 + c] = r[m];
    __syncthreads();
    if (j >= 8) {
#pragma unroll
        for (int jj = 0; jj < 16; jj++) r2[jj] = T[(jj + 16 * (j - 8)) * TP32 + c];
    }
#pragma unroll
    for (int q = 0; q < 4; q++) bf4f(r2[q], r2[q + 4], r2[q + 8], r2[q + 12], tw, 16, q);
#pragma unroll
    for (int h = 0; h < 4; h++) bf4f(r2[4 * h], r2[4 * h + 1], r2[4 * h + 2], r2[4 * h + 3], tw, 64, 0);
#pragma unroll
    for (int jj = 0; jj < 16; jj++) {
        int p = jj + 16 * j;
        int k2 = dr4(p);
        int ph = (n1 * k2) & (L - 1);
        float2 w = cmul(tw[ph >> 8], fine[ph & 255]);
        tile[(p << 5) + c] = __float22half2_rn(cmul(r2[jj], w));
    }
}

// ---- pointwise unit (LDS form), Y scaled by PW_SCALE ----
__device__ __forceinline__ void pw_unit(float2* A, int sJ, int kJ, int sN, int kN) {
    float2 Z0j = A[sJ * ROWP + kJ],       Z0n = A[sN * ROWP + kN];
    float2 Z1j = A[(4 + sJ) * ROWP + kJ], Z1n = A[(4 + sN) * ROWP + kN];
    float2 D0 = make_float2(0.5f * (Z0j.x + Z0n.x), 0.5f * (Z0j.y - Z0n.y));
    float2 K0 = make_float2(0.5f * (Z0j.y + Z0n.y), 0.5f * (Z0n.x - Z0j.x));
    float2 D1 = make_float2(0.5f * (Z1j.x + Z1n.x), 0.5f * (Z1j.y - Z1n.y));
    float2 K1 = make_float2(0.5f * (Z1j.y + Z1n.y), 0.5f * (Z1n.x - Z1j.x));
    float2 W0 = cmul(D0, K0);
    float2 W1 = cmul(D1, K1);
    A[sJ * ROWP + kJ] = make_float2((W0.x - W1.y) * PW_SCALE, (W0.y + W1.x) * PW_SCALE);
    A[sN * ROWP + kN] = make_float2((W0.x + W1.y) * PW_SCALE, (W1.x - W0.y) * PW_SCALE);
}

// ---- fused row pass over 32-col tiles ----
__global__ void k_rowpw(__half2* __restrict__ C) {
    __shared__ float2 A[8 * ROWP];
    __shared__ float2 tw[192];
    int t = threadIdx.x;
    int p = blockIdx.x >> 6;
    int g = blockIdx.x & 63;
    int rows[4];
    if (g == 0) { rows[0] = 0; rows[1] = 1; rows[2] = 128; rows[3] = 255; }
    else        { rows[0] = 2 * g; rows[1] = 2 * g + 1; rows[2] = 256 - 2 * g; rows[3] = 255 - 2 * g; }
    if (t < 192) {
        float sv, cv;
        __sincosf(-TWO_PI * (float)t * (1.0f / 256.0f), &sv, &cv);
        tw[t] = make_float2(cv, sv);
    }
    __half2* b0 = C + ((size_t)(2 * p) * 8) * TILE32;
    __half2* b1 = b0 + 8 * TILE32;
    for (int u = t; u < 512; u += 256) {
        int slot = u >> 6;               // 0..7
        int f = (u & 63) << 2;           // n1 start (mult of 4)
        int cg = f >> 5, c2 = f & 31;
        const __half2* arr = (slot < 4) ? b0 : b1;
        int grow = dr4(rows[slot & 3]);
        float4 raw = *(const float4*)(arr + cg * TILE32 + (grow << 5) + c2);
        const __half2* hp = (const __half2*)&raw;
        A[slot * ROWP + f]     = __half22float2(hp[0]);
        A[slot * ROWP + f + 1] = __half22float2(hp[1]);
        A[slot * ROWP + f + 2] = __half22float2(hp[2]);
        A[slot * ROWP + f + 3] = __half22float2(hp[3]);
    }
    __syncthreads();
#pragma unroll
    for (int lm = 8; lm >= 6; lm -= 2) {
        int Q = 1 << (lm - 2), f = 256 >> lm;
        for (int u = t; u < 512; u += 256) {
            int row = u >> 6, qi = u & 63;
            int q = qi & (Q - 1);
            int i0 = ((qi - q) << 2) + q;
            bfly4_fwd(A, row * ROWP + i0, Q, tw, f, q);
        }
        __syncthreads();
    }
#pragma unroll
    for (int lm = 4; lm >= 2; lm -= 2) {
        int Q = 1 << (lm - 2), f = 256 >> lm;
        for (int u = t; u < 512; u += 256) {
            int row = u & 7, qi = u >> 3;
            int q = qi & (Q - 1);
            int i0 = ((qi - q) << 2) + q;
            bfly4_fwd(A, row * ROWP + i0, Q, tw, f, q);
        }
        __syncthreads();
    }
    if (g) {
        pw_unit(A, 0, t, 2, 255 - t);
    } else {
        if (t == 0)      { pw_unit(A, 0, 0, 0, 0); pw_unit(A, 0, 2, 0, 2); }
        else if (t < 128) pw_unit(A, 0, dr4(t), 0, dr4(256 - t));
        else              { int qq = t - 128; pw_unit(A, 2, qq, 2, 255 - qq); }
    }
    pw_unit(A, 1, t, 3, 255 - t);
    __syncthreads();
#pragma unroll
    for (int lm = 2; lm <= 4; lm += 2) {
        int Q = 1 << (lm - 2), f = 256 >> lm;
        int row = t & 3, qi = t >> 2;
        int q = qi & (Q - 1);
        int i0 = ((qi - q) << 2) + q;
        bfly4_inv(A, row * ROWP + i0, Q, tw, f, q);
        __syncthreads();
    }
#pragma unroll
    for (int lm = 6; lm <= 8; lm += 2) {
        int Q = 1 << (lm - 2), f = 256 >> lm;
        int row = t >> 6, qi = t & 63;
        int q = qi & (Q - 1);
        int i0 = ((qi - q) << 2) + q;
        bfly4_inv(A, row * ROWP + i0, Q, tw, f, q);
        __syncthreads();
    }
    {
        int u = t;
        int slot = u >> 6;               // 0..3
        int f = (u & 63) << 2;
        int cg = f >> 5, c2 = f & 31;
        int r = rows[slot];
        __half2 outv[4];
#pragma unroll
        for (int i = 0; i < 4; i++) {
            float2 v = A[slot * ROWP + f + i];
            int ph = ((f + i) * r) & (L - 1);
            float sv, cv;
            __sincosf(TWO_PI * (float)ph * INV_L, &sv, &cv);
            outv[i] = __float22half2_rn(cmul(v, make_float2(cv, sv)));
        }
        *(float4*)(b0 + cg * TILE32 + (dr4(r) << 5) + c2) = *(float4*)outv;
    }
}

// ---- inverse col pass: parallel inline mix-gate, contiguous tile reads, fp16 out ----
__global__ __launch_bounds__(512) void k_colinv(const __half2* __restrict__ C,
                                                const __half* __restrict__ dryfh,
                                                const float* __restrict__ g,
                                                const float* __restrict__ w_mix,
                                                const float* __restrict__ b_mix,
                                                __half* __restrict__ mixo,
                                                float* __restrict__ partial) {
    __shared__ float2 T[128 * TP32];
    __shared__ float2 tw[256];
    __shared__ float mpart[256];
    __shared__ float sm0[8], sm1[8];
    __shared__ float smix[2];
    int t = threadIdx.x;
    int a = blockIdx.x >> 3;       // pair
    int cgrp = blockIdx.x & 7;     // 8 x 32 columns
    int c0 = cgrp * 32;
    const __half2* tile = C + ((size_t)(2 * a * 8 + cgrp)) * TILE32;
    if (t < 256) {
        float sv, cv;
        __sincosf(-TWO_PI * (float)t * (1.0f / 256.0f), &sv, &cv);
        tw[t] = make_float2(cv, sv);
        int bb = t >> 7, d = t & 127;
        mpart[t] = g[(2 * a + bb) * DGATE + d] * w_mix[d];
    }
    int j = t >> 5, c = t & 31;
    int n1 = c0 + c;
    float2 r[16];
#pragma unroll
    for (int jj = 0; jj < 16; jj++)
        r[jj] = __half22float2(tile[((jj + 16 * j) << 5) + c]);
    __syncthreads();
    if (t < 2) {
        float acc = b_mix[0];
#pragma unroll
        for (int i = 0; i < 128; i++) acc += mpart[(t << 7) + i];
        smix[t] = 1.f / (1.f + expf(-acc));
    }
#pragma unroll
    for (int h = 0; h < 4; h++) bf4i(r[4 * h], r[4 * h + 1], r[4 * h + 2], r[4 * h + 3], tw, 64, 0);
#pragma unroll
    for (int q = 0; q < 4; q++) bf4i(r[q], r[q + 4], r[q + 8], r[q + 12], tw, 16, q);
    float2 r2[16];
    if (j < 8) {
#pragma unroll
        for (int jj = 0; jj < 16; jj++) T[(jj + 16 * j) * TP32 + c] = r[jj];
    }
    __syncthreads();
#pragma unroll
    for (int m = 0; m < 8; m++) r2[m] = T[(j + 16 * m) * TP32 + c];
    __syncthreads();
    if (j >= 8) {
#pragma unroll
        for (int jj = 0; jj < 16; jj++) T[(16 * (j - 8) + jj) * TP32 + c] = r[jj];
    }
    __syncthreads();
#pragma unroll
    for (int m = 8; m < 16; m++) r2[m] = T[(j + 16 * (m - 8)) * TP32 + c];
#pragma unroll
    for (int h = 0; h < 4; h++) bf4i(r2[4 * h], r2[4 * h + 1], r2[4 * h + 2], r2[4 * h + 3], tw, 4, j);
#pragma unroll
    for (int m0 = 0; m0 < 4; m0++) bf4i(r2[m0], r2[m0 + 4], r2[m0 + 8], r2[m0 + 12], tw, 1, j + 16 * m0);
    int b0 = 2 * a, b1 = 2 * a + 1;
    float mix0 = smix[0], mix1 = smix[1];
    float om0 = 1.f - mix0, om1 = 1.f - mix1;
    const __half* dry0 = dryfh + (size_t)b0 * N_T;
    const __half* dry1 = dryfh + (size_t)b1 * N_T;
    __half* mo0 = mixo + (size_t)b0 * N_T;
    __half* mo1 = mixo + (size_t)b1 * N_T;
    float m0 = -3.4e38f, m1 = -3.4e38f;
#pragma unroll
    for (int m = 0; m < 8; m++) {
        int pos = n1 + ((j + 16 * m) << 8);      // n2 = j+16m < 128
        float d0 = __half2float(dry0[pos]), d1 = __half2float(dry1[pos]);
        float o0 = mix0 * (r2[m].x * COL_SCALE) + om0 * d0;
        float o1 = mix1 * (r2[m].y * COL_SCALE) + om1 * d1;
        mo0[pos] = __float2half(o0);
        mo1[pos] = __float2half(o1);
        m0 = fmaxf(m0, o0);
        m1 = fmaxf(m1, o1);
    }
#pragma unroll
    for (int off = 32; off > 0; off >>= 1) {
        m0 = fmaxf(m0, __shfl_down(m0, off));
        m1 = fmaxf(m1, __shfl_down(m1, off));
    }
    if ((t & 63) == 0) { sm0[t >> 6] = m0; sm1[t >> 6] = m1; }
    __syncthreads();
    if (t == 0) {
        float p0 = sm0[0], p1 = sm1[0];
#pragma unroll
        for (int w = 1; w < 8; w++) { p0 = fmaxf(p0, sm0[w]); p1 = fmaxf(p1, sm1[w]); }
        partial[b0 * 8 + cgrp] = p0;
        partial[b1 * 8 + cgrp] = p1;
    }
}

// ---- normalize: read fp16 mixed output, divide by row max, write fp32 out ----
__global__ void k_norm(const __half* __restrict__ mixo, const float* __restrict__ partial,
                       float* __restrict__ out) {
    int blk = blockIdx.x;
    int b = blk >> 5;
    int ch = blk & 31;
    __shared__ float smx;
    if (threadIdx.x < 8) {
        float p = partial[b * 8 + threadIdx.x];
#pragma unroll
        for (int off = 4; off > 0; off >>= 1) p = fmaxf(p, __shfl_down(p, off, 8));
        if (threadIdx.x == 0) smx = p;
    }
    __syncthreads();
    float inv = 1.f / (smx + 1e-8f);
    size_t base = (size_t)b * N_T + ch * 1024 + threadIdx.x * 4;
    float2 hraw = *(const float2*)(mixo + base);
    const __half2* hp = (const __half2*)&hraw;
    float2 v0 = __half22float2(hp[0]);
    float2 v1 = __half22float2(hp[1]);
    float4 o = make_float4(v0.x * inv, v0.y * inv, v1.x * inv, v1.y * inv);
    *(float4*)(out + base) = o;
}

extern "C" void kernel_launch(void* const* d_in, const int* in_sizes, int n_in,
                              void* d_out, int out_size, void* d_ws, size_t ws_size,
                              hipStream_t stream) {
    const float* events = (const float*)d_in[0];
    const int* indices = (const int*)d_in[1];
    const float* g      = (const float*)d_in[2];
    const float* rooms  = (const float*)d_in[3];
    const float* w_room = (const float*)d_in[4];
    const float* b_room = (const float*)d_in[5];
    const float* w_mix  = (const float*)d_in[6];
    const float* b_mix  = (const float*)d_in[7];
    float* out = (float*)d_out;

    char* ws = (char*)d_ws;
    __half2* C = (__half2*)ws;               // [64 batches][8 tiles][256 p][32 c] half2 = 16 MB
    size_t off = (size_t)BATCH * L * sizeof(__half2);
    __half* dryfh = (__half*)(ws + off);     // 4 MB
    off += (size_t)BATCH * N_T * sizeof(__half);
    __half* mixo = (__half*)(ws + off);      // 4 MB
    off += (size_t)BATCH * N_T * sizeof(__half);
    float* partial = (float*)(ws + off);

    k_fwd<<<BATCH * 8, 512, 0, stream>>>(events, indices, rooms, g, w_room, b_room, dryfh, C);
    k_rowpw<<<NPAIR * 64, 256, 0, stream>>>(C);
    k_colinv<<<NPAIR * 8, 512, 0, stream>>>(C, dryfh, g, w_mix, b_mix, mixo, partial);
    k_norm<<<BATCH * 32, 256, 0, stream>>>(mixo, partial, out);
}